// Round 1
// baseline (274.649 us; speedup 1.0000x reference)
//
#include <hip/hip_runtime.h>

// ---- problem constants ----
#define PS   10
#define KNN  7
#define WSZ  29
#define RR   14
#define IH   96
#define IW   96
#define CH   16
#define CE   8
#define HH   98            // h after pad1
#define W2   107           // H + PS - 1
#define QN   (HH*HH)       // 9604 queries
#define ND   (WSZ*WSZ)     // 841 displacements
#define XTW  124           // padded transposed x: coords [-14,109] -> 124
#define XTP  14

#define CHUNK 281          // displacement chunk (3 chunks: 281,281,279)

// ---- ws layout (float units) ----
#define DIST_FLOATS ((size_t)CHUNK * QN)                     // 2,698,724
#define OFF_SV  (((DIST_FLOATS) + 63) & ~(size_t)63)         // QN*8 floats (topk vals -> weights)
#define OFF_SD  (OFF_SV + (size_t)QN*8)                      // QN*8 ints  (topk disp -> deltas)
#define OFF_XT  (((OFF_SD + (size_t)QN*8) + 63) & ~(size_t)63) // XTW*XTW*CH floats

__device__ __forceinline__ int imin(int a, int b){ return a<b?a:b; }
__device__ __forceinline__ int imax(int a, int b){ return a>b?a:b; }

// ---- K0: x (16,96,96) -> xT[124][124][16], zero-padded by 14 ----
__global__ __launch_bounds__(256) void k_transpose(const float* __restrict__ x,
                                                   float* __restrict__ xT) {
    int t = blockIdx.x*256 + threadIdx.x;
    if (t >= XTW*XTW) return;
    int u = t / XTW, v = t % XTW;
    int ui = u - XTP, vi = v - XTP;
    bool inb = ((unsigned)ui < (unsigned)IH) && ((unsigned)vi < (unsigned)IW);
    int off = inb ? (ui*IW + vi) : 0;
    float4* dst = (float4*)(xT + (size_t)t*CH);
    #pragma unroll
    for (int c4 = 0; c4 < 4; ++c4) {
        float4 val;
        val.x = inb ? x[(c4*4+0)*IH*IW + off] : 0.f;
        val.y = inb ? x[(c4*4+1)*IH*IW + off] : 0.f;
        val.z = inb ? x[(c4*4+2)*IH*IW + off] : 0.f;
        val.w = inb ? x[(c4*4+3)*IH*IW + off] : 0.f;
        dst[c4] = val;
    }
}

// ---- K1: per-displacement patch L2 distances (separable box sums) ----
// block = one displacement of the chunk. cs[y0][j] = vertical 10-sum of sq.
__global__ __launch_bounds__(256) void k_dist(const float* __restrict__ xe,
                                              const float* __restrict__ ye,
                                              float* __restrict__ dist, int d_base) {
    __shared__ float cs[HH * W2];          // 98*107*4 = 41,944 B
    int dd = blockIdx.x;
    int d  = d_base + dd;
    int dy = d / WSZ - RR, dx = d % WSZ - RR;
    int t  = threadIdx.x;

    if (t < 2*W2) {
        int strip = t / W2;                 // 0: rows 0..48, 1: rows 49..97
        int j     = t % W2;
        int y0s   = strip * 49;
        bool jy = (unsigned)(j - 6)      < (unsigned)IW;
        bool jx = (unsigned)(j + dx - 6) < (unsigned)IW;
        int jyo = jy ? (j - 6)      : 0;
        int jxo = jx ? (j + dx - 6) : 0;

        auto SQ = [&](int i) -> float {
            int yi = i - 6, xi = i + dy - 6;
            bool yok = jy && ((unsigned)yi < (unsigned)IH);
            bool xok = jx && ((unsigned)xi < (unsigned)IH);
            int yoff = yok ? (yi*IW + jyo) : 0;
            int xoff = xok ? (xi*IW + jxo) : 0;
            float acc = 0.f;
            #pragma unroll
            for (int c = 0; c < CE; ++c) {
                float yv = yok ? ye[c*IH*IW + yoff] : 0.f;
                float xv = xok ? xe[c*IH*IW + xoff] : 0.f;
                float dl = yv - xv;
                acc = fmaf(dl, dl, acc);
            }
            return acc;
        };

        float w[9]; float sumw = 0.f;
        #pragma unroll
        for (int r = 0; r < 9; ++r) { w[r] = SQ(y0s + r); sumw += w[r]; }
        for (int y0 = y0s; y0 < y0s + 49; ++y0) {
            float nv  = SQ(y0 + 9);
            float tot = sumw + nv;
            cs[y0*W2 + j] = tot;
            sumw = tot - w[0];
            #pragma unroll
            for (int r = 0; r < 8; ++r) w[r] = w[r+1];
            w[8] = nv;
        }
    }
    __syncthreads();

    bool self = (dy == 0) && (dx == 0);
    for (int idx = t; idx < QN; idx += 256) {
        int y0 = idx / HH, x0 = idx % HH;
        const float* row = cs + y0*W2 + x0;
        float s = 0.f;
        #pragma unroll
        for (int ox = 0; ox < PS; ++ox) s += row[ox];
        int ni = y0 + dy, nj = x0 + dx;
        bool valid = ((unsigned)ni < 98u) && ((unsigned)nj < 98u) && !self;
        dist[(size_t)dd*QN + idx] = valid ? s : 1e10f;
    }
}

// ---- K2: top-7 merge per query (one wave per query), chunked ----
// mode bit0: init (skip state load); bit1: final (softmax + delta conversion)
__global__ __launch_bounds__(256) void k_topk(const float* __restrict__ dist,
                                              float* __restrict__ sv, int* __restrict__ sd,
                                              int d_base, int nd, int mode) {
    int gw   = (blockIdx.x*256 + threadIdx.x) >> 6;
    int lane = threadIdx.x & 63;
    if (gw >= QN) return;
    int q = gw;

    float ld[KNN]; int li[KNN];
    #pragma unroll
    for (int k = 0; k < KNN; ++k) { ld[k] = 1e30f; li[k] = -1; }

    auto INS = [&](float v, int dsp) {
        float cv = v; int ci = dsp;
        #pragma unroll
        for (int k = 0; k < KNN; ++k) {
            bool sw = cv < ld[k];
            float tf = ld[k]; int ti = li[k];
            ld[k] = sw ? cv : tf;  li[k] = sw ? ci : ti;
            cv    = sw ? tf : cv;  ci    = sw ? ti : ci;
        }
    };

    #pragma unroll
    for (int c = 0; c < 5; ++c) {           // 64*5=320 >= 281
        int dd = lane*5 + c;
        if (dd < nd) INS(dist[(size_t)dd*QN + q], d_base + dd);
    }
    if (!(mode & 1)) {
        if (lane < KNN) INS(sv[q*8 + lane], sd[q*8 + lane]);
    }

    float tv[KNN]; int td[KNN];
    #pragma unroll
    for (int r = 0; r < KNN; ++r) {
        float bv = ld[0]; int bd = li[0];
        #pragma unroll
        for (int s = 1; s < 64; s <<= 1) {
            float ov = __shfl_xor(bv, s, 64);
            int   od = __shfl_xor(bd, s, 64);
            if (ov < bv || (ov == bv && (unsigned)od < (unsigned)bd)) { bv = ov; bd = od; }
        }
        tv[r] = bv; td[r] = bd;
        if (li[0] == bd) {
            #pragma unroll
            for (int k = 0; k < KNN-1; ++k) { ld[k] = ld[k+1]; li[k] = li[k+1]; }
            ld[KNN-1] = 1e30f; li[KNN-1] = -1;
        }
    }

    if (mode & 2) {
        float e[KNN]; float ssum = 0.f;
        #pragma unroll
        for (int r = 0; r < KNN; ++r) { e[r] = expf(tv[0] - tv[r]); ssum += e[r]; }
        float inv = 1.f / ssum;
        if (lane == 0) {
            #pragma unroll
            for (int r = 0; r < KNN; ++r) {
                sv[q*8 + r] = e[r] * inv;
                int dsp = td[r];
                int dy = dsp / WSZ - RR, dx = dsp % WSZ - RR;
                sd[q*8 + r] = (dy*XTW + dx) * CH;     // float-unit delta into xT
            }
        }
    } else {
        if (lane == 0) {
            #pragma unroll
            for (int r = 0; r < KNN; ++r) { sv[q*8 + r] = tv[r]; sd[q*8 + r] = td[r]; }
        }
    }
}

// ---- K3: aggregation gather + fold-normalize + output (both halves) ----
__global__ __launch_bounds__(256) void k_agg(const float* __restrict__ xT,
                                             const float* __restrict__ wgt,
                                             const int* __restrict__ dlt,
                                             float* __restrict__ out) {
    int tid  = blockIdx.x*256 + threadIdx.x;
    int p    = tid >> 2, quad = tid & 3;
    if (p >= IH*IW) return;
    int ai = p / IW, bi = p % IW;
    int i = ai + 6, j = bi + 6;                    // vid coords
    int base = ((ai + XTP)*XTW + (bi + XTP))*CH + quad*4;

    float a0x=0,a0y=0,a0z=0,a0w=0, a1x=0,a1y=0,a1z=0,a1w=0;
    for (int oy = 0; oy < PS; ++oy) {
        int qi = i - oy;
        if ((unsigned)qi >= 98u) continue;
        for (int ox = 0; ox < PS; ++ox) {
            int qj = j - ox;
            if ((unsigned)qj >= 98u) continue;
            int q = qi*HH + qj;
            const float* wp = wgt + q*8;
            const int*   dp = dlt + q*8;
            #pragma unroll
            for (int k = 0; k < KNN; ++k) {
                float wk = wp[k];
                int   dl = dp[k];
                const float4 xv = *(const float4*)(xT + base + dl);
                if (k & 1) {
                    a1x = fmaf(wk, xv.x, a1x); a1y = fmaf(wk, xv.y, a1y);
                    a1z = fmaf(wk, xv.z, a1z); a1w = fmaf(wk, xv.w, a1w);
                } else {
                    a0x = fmaf(wk, xv.x, a0x); a0y = fmaf(wk, xv.y, a0y);
                    a0z = fmaf(wk, xv.z, a0z); a0w = fmaf(wk, xv.w, a0w);
                }
            }
        }
    }
    float ax = a0x+a1x, ay = a0y+a1y, az = a0z+a1z, aw = a0w+a1w;

    float cr = (float)(imin(i, 97) - imax(i - 9, 0) + 1);
    float cc = (float)(imin(j, 97) - imax(j - 9, 0) + 1);
    float inv = 1.f / (cr * cc);
    float4 xs = *(const float4*)(xT + base);

    int ch0 = quad*4;
    out[(ch0+0)*IH*IW + p] = xs.x;
    out[(ch0+1)*IH*IW + p] = xs.y;
    out[(ch0+2)*IH*IW + p] = xs.z;
    out[(ch0+3)*IH*IW + p] = xs.w;
    out[(16+ch0+0)*IH*IW + p] = ax*inv - xs.x;
    out[(16+ch0+1)*IH*IW + p] = ay*inv - xs.y;
    out[(16+ch0+2)*IH*IW + p] = az*inv - xs.z;
    out[(16+ch0+3)*IH*IW + p] = aw*inv - xs.w;
}

extern "C" void kernel_launch(void* const* d_in, const int* in_sizes, int n_in,
                              void* d_out, int out_size, void* d_ws, size_t ws_size,
                              hipStream_t stream) {
    const float* x  = (const float*)d_in[0];
    const float* xe = (const float*)d_in[1];
    const float* ye = (const float*)d_in[2];
    float* out = (float*)d_out;
    float* ws  = (float*)d_ws;

    float* dist = ws;
    float* sv   = ws + OFF_SV;
    int*   sd   = (int*)(ws + OFF_SD);
    float* xT   = ws + OFF_XT;

    hipLaunchKernelGGL(k_transpose, dim3((XTW*XTW + 255)/256), dim3(256), 0, stream, x, xT);

    int base = 0;
    const int nds[3] = {281, 281, 279};
    for (int c = 0; c < 3; ++c) {
        int nd = nds[c];
        hipLaunchKernelGGL(k_dist, dim3(nd), dim3(256), 0, stream, xe, ye, dist, base);
        int mode = (c == 0 ? 1 : 0) | (c == 2 ? 2 : 0);
        hipLaunchKernelGGL(k_topk, dim3((QN + 3)/4), dim3(256), 0, stream, dist, sv, sd, base, nd, mode);
        base += nd;
    }

    hipLaunchKernelGGL(k_agg, dim3((IH*IW*4 + 255)/256), dim3(256), 0, stream, xT, sv, sd, out);
}

// Round 2
// 166.641 us; speedup vs baseline: 1.6481x; 1.6481x over previous
//
#include <hip/hip_runtime.h>

// ---- problem constants ----
#define PS   10
#define KNN  7
#define WSZ  29
#define RR   14
#define IH   96
#define IW   96
#define CH   16
#define CE   8
#define HH   98            // query grid (after pad1)
#define W2   107           // HH + PS - 1
#define QN   (HH*HH)       // 9604 queries
#define ND   (WSZ*WSZ)     // 841 displacements
#define XTW  124           // padded x-interleaved: coords [-14,109]
#define XTP  14
#define YEW  107
#define YEH  112           // rows alloc (phase-A overreads to row 108)
#define XEW  136
#define XEH  140

#define CHUNK 281

// ---- ws layout (float units) ----
#define OFF_SV   2698752ull                       // align64(281*9604)
#define OFF_SD   (OFF_SV + 76832ull)
#define OFF_XT   (OFF_SD + 76832ull)              // 2,852,416
#define OFF_YEP  (OFF_XT + 246016ull)             // 3,098,432
#define OFF_XEP  (OFF_YEP + (size_t)(YEH*YEW*CE)) // 3,194,304
// total = 3,346,624 floats = 13.4 MB

__device__ __forceinline__ int imin(int a, int b){ return a<b?a:b; }
__device__ __forceinline__ int imax(int a, int b){ return a>b?a:b; }

// ---- K0: pack x -> xT[124][124][16]; ye -> yeP[112][107][8]; xe -> xeP[140][136][8]
__global__ __launch_bounds__(256) void k_prep(const float* __restrict__ x,
                                              const float* __restrict__ xe,
                                              const float* __restrict__ ye,
                                              float* __restrict__ xT,
                                              float* __restrict__ xeP,
                                              float* __restrict__ yeP) {
    int t = blockIdx.x*256 + threadIdx.x;
    if (t < XTW*XTW) {
        int u = t / XTW, v = t % XTW;
        int ui = u - XTP, vi = v - XTP;
        bool inb = ((unsigned)ui < (unsigned)IH) && ((unsigned)vi < (unsigned)IW);
        int off = inb ? (ui*IW + vi) : 0;
        float4* dst = (float4*)(xT + (size_t)t*CH);
        #pragma unroll
        for (int c4 = 0; c4 < 4; ++c4) {
            float4 val;
            val.x = inb ? x[(c4*4+0)*IH*IW + off] : 0.f;
            val.y = inb ? x[(c4*4+1)*IH*IW + off] : 0.f;
            val.z = inb ? x[(c4*4+2)*IH*IW + off] : 0.f;
            val.w = inb ? x[(c4*4+3)*IH*IW + off] : 0.f;
            dst[c4] = val;
        }
        return;
    }
    t -= XTW*XTW;
    if (t < YEH*YEW) {
        int i = t / YEW, j = t % YEW;
        bool inb = ((unsigned)(i-6) < (unsigned)IH) && ((unsigned)(j-6) < (unsigned)IW);
        int off = inb ? ((i-6)*IW + (j-6)) : 0;
        float4* dst = (float4*)(yeP + (size_t)t*CE);
        #pragma unroll
        for (int c4 = 0; c4 < 2; ++c4) {
            float4 val;
            val.x = inb ? ye[(c4*4+0)*IH*IW + off] : 0.f;
            val.y = inb ? ye[(c4*4+1)*IH*IW + off] : 0.f;
            val.z = inb ? ye[(c4*4+2)*IH*IW + off] : 0.f;
            val.w = inb ? ye[(c4*4+3)*IH*IW + off] : 0.f;
            dst[c4] = val;
        }
        return;
    }
    t -= YEH*YEW;
    if (t < XEH*XEW) {
        int i = t / XEW, j = t % XEW;
        bool inb = ((unsigned)(i-20) < (unsigned)IH) && ((unsigned)(j-20) < (unsigned)IW);
        int off = inb ? ((i-20)*IW + (j-20)) : 0;
        float4* dst = (float4*)(xeP + (size_t)t*CE);
        #pragma unroll
        for (int c4 = 0; c4 < 2; ++c4) {
            float4 val;
            val.x = inb ? xe[(c4*4+0)*IH*IW + off] : 0.f;
            val.y = inb ? xe[(c4*4+1)*IH*IW + off] : 0.f;
            val.z = inb ? xe[(c4*4+2)*IH*IW + off] : 0.f;
            val.w = inb ? xe[(c4*4+3)*IH*IW + off] : 0.f;
            dst[c4] = val;
        }
    }
}

// ---- K1: patch L2 distances. block = (displacement, row-strip of 25 query rows)
__global__ __launch_bounds__(128) void k_dist(const float* __restrict__ xeP,
                                              const float* __restrict__ yeP,
                                              float* __restrict__ dist, int d_base) {
    __shared__ float sq[34*107];   // 14552 B
    __shared__ float cs[25*107];   // 10700 B
    int dd    = blockIdx.x >> 2;
    int strip = blockIdx.x & 3;
    int d  = d_base + dd;
    int dy = d / WSZ - RR, dx = d % WSZ - RR;
    int t  = threadIdx.x;
    int y0s = strip * 25;
    int nrows = imin(25, HH - y0s);      // 25,25,25,23

    // phase A: squared-diff field (channel-summed)
    int xoff0 = ((dy + 14) * XEW + (dx + 14)) * CE;
    for (int u = t; u < 34*107; u += 128) {
        int r = u / 107, j = u - r*107;
        int i = y0s + r;
        const float4* yp = (const float4*)(yeP + (size_t)(i*YEW + j)*CE);
        const float4* xp = (const float4*)(xeP + (size_t)(i*XEW + j)*CE + xoff0);
        float4 ya = yp[0], yb = yp[1], xa = xp[0], xb = xp[1];
        float d0 = ya.x-xa.x, d1 = ya.y-xa.y, d2 = ya.z-xa.z, d3 = ya.w-xa.w;
        float d4 = yb.x-xb.x, d5 = yb.y-xb.y, d6 = yb.z-xb.z, d7 = yb.w-xb.w;
        float acc = d0*d0;
        acc = fmaf(d1,d1,acc); acc = fmaf(d2,d2,acc); acc = fmaf(d3,d3,acc);
        acc = fmaf(d4,d4,acc); acc = fmaf(d5,d5,acc); acc = fmaf(d6,d6,acc);
        acc = fmaf(d7,d7,acc);
        sq[u] = acc;
    }
    __syncthreads();

    // phase B: vertical 10-sums
    for (int u = t; u < 25*107; u += 128) {
        float s = sq[u];
        #pragma unroll
        for (int k = 1; k < PS; ++k) s += sq[u + k*107];
        cs[u] = s;
    }
    __syncthreads();

    // phase C: horizontal 10-sums -> dist
    bool self = (dy == 0) && (dx == 0);
    for (int u = t; u < nrows*98; u += 128) {
        int r = u / 98, x0 = u - r*98;
        int y0 = y0s + r;
        const float* row = cs + r*107 + x0;
        float s = row[0];
        #pragma unroll
        for (int ox = 1; ox < PS; ++ox) s += row[ox];
        int ni = y0 + dy, nj = x0 + dx;
        bool valid = ((unsigned)ni < 98u) && ((unsigned)nj < 98u) && !self;
        dist[(size_t)dd*QN + y0*98 + x0] = valid ? s : 1e10f;
    }
}

// ---- K2: per-lane top-7; 4 waves split the displacements, LDS merge ----
__global__ __launch_bounds__(256) void k_topk(const float* __restrict__ dist,
                                              float* __restrict__ sv, int* __restrict__ sd,
                                              int d_base, int nd, int mode) {
    __shared__ float lv[3*64*8];
    __shared__ int   lix[3*64*8];
    int wv = threadIdx.x >> 6, ln = threadIdx.x & 63;
    int q = blockIdx.x*64 + ln;
    bool qok = q < QN;

    float ld[KNN]; int li[KNN];
    #pragma unroll
    for (int k = 0; k < KNN; ++k) { ld[k] = 1e30f; li[k] = -1; }

    auto INS = [&](float v, int dsp) {
        float cv = v; int ci = dsp;
        #pragma unroll
        for (int k = 0; k < KNN; ++k) {
            bool sw = cv < ld[k];
            float tf = ld[k]; int ti = li[k];
            ld[k] = sw ? cv : tf;  li[k] = sw ? ci : ti;
            cv    = sw ? tf : cv;  ci    = sw ? ti : ci;
        }
    };

    int ndq = (nd + 3) >> 2;
    int s0 = wv * ndq, s1 = imin(nd, s0 + ndq);
    if (qok) {
        #pragma unroll 2
        for (int dd = s0; dd < s1; ++dd)
            INS(dist[(size_t)dd*QN + q], d_base + dd);
        if (wv == 0 && !(mode & 1)) {
            #pragma unroll
            for (int r = 0; r < KNN; ++r) INS(sv[q*8 + r], sd[q*8 + r]);
        }
    }
    if (wv) {
        int b = ((wv-1)*64 + ln)*8;
        #pragma unroll
        for (int r = 0; r < KNN; ++r) { lv[b+r] = ld[r]; lix[b+r] = li[r]; }
    }
    __syncthreads();
    if (wv == 0 && qok) {
        #pragma unroll
        for (int w = 0; w < 3; ++w) {
            int b = (w*64 + ln)*8;
            #pragma unroll
            for (int r = 0; r < KNN; ++r) INS(lv[b+r], lix[b+r]);
        }
        if (mode & 2) {
            float e[KNN]; float ssum = 0.f;
            #pragma unroll
            for (int r = 0; r < KNN; ++r) { e[r] = __expf(ld[0] - ld[r]); ssum += e[r]; }
            float inv = 1.f / ssum;
            #pragma unroll
            for (int r = 0; r < KNN; ++r) {
                sv[q*8 + r] = e[r] * inv;
                int dsp = li[r];
                int dyk = dsp / WSZ - RR, dxk = dsp % WSZ - RR;
                sd[q*8 + r] = (dyk*XTW + dxk) * CH;    // float-unit delta into xT
            }
        } else {
            #pragma unroll
            for (int r = 0; r < KNN; ++r) { sv[q*8 + r] = ld[r]; sd[q*8 + r] = li[r]; }
        }
    }
}

// ---- K3: aggregation gather; 4 waves split the 100 (oy,ox) positions ----
__global__ __launch_bounds__(256) void k_agg(const float* __restrict__ xT,
                                             const float* __restrict__ wgt,
                                             const int* __restrict__ dlt,
                                             float* __restrict__ out) {
    __shared__ float4 red[192];
    int wv = threadIdx.x >> 6, ln = threadIdx.x & 63;
    int pq = blockIdx.x*64 + ln;          // 16 pixels x 4 quads per block
    int p = pq >> 2, quad = pq & 3;
    int ai = p / IW, bi = p % IW;
    int i = ai + 6, j = bi + 6;
    int base = ((ai + XTP)*XTW + (bi + XTP))*CH + quad*4;

    float a0x=0,a0y=0,a0z=0,a0w=0, a1x=0,a1y=0,a1z=0,a1w=0;
    #pragma unroll
    for (int c = 0; c < 25; ++c) {
        int u = wv*25 + c;
        int oy = u / 10, ox = u - oy*10;
        int qi = i - oy;
        int qj = j - ox;
        if (((unsigned)qi >= 98u) || ((unsigned)qj >= 98u)) continue;
        int q = qi*HH + qj;
        const float* wp = wgt + q*8;
        const int*   dp = dlt + q*8;
        #pragma unroll
        for (int k = 0; k < KNN; ++k) {
            float wk = wp[k];
            int   dl = dp[k];
            const float4 xv = *(const float4*)(xT + base + dl);
            if (k & 1) {
                a1x = fmaf(wk, xv.x, a1x); a1y = fmaf(wk, xv.y, a1y);
                a1z = fmaf(wk, xv.z, a1z); a1w = fmaf(wk, xv.w, a1w);
            } else {
                a0x = fmaf(wk, xv.x, a0x); a0y = fmaf(wk, xv.y, a0y);
                a0z = fmaf(wk, xv.z, a0z); a0w = fmaf(wk, xv.w, a0w);
            }
        }
    }
    float4 part;
    part.x = a0x+a1x; part.y = a0y+a1y; part.z = a0z+a1z; part.w = a0w+a1w;

    if (wv) red[(wv-1)*64 + ln] = part;
    __syncthreads();
    if (wv == 0) {
        float4 r0 = red[ln], r1 = red[64+ln], r2 = red[128+ln];
        float ax = part.x + r0.x + r1.x + r2.x;
        float ay = part.y + r0.y + r1.y + r2.y;
        float az = part.z + r0.z + r1.z + r2.z;
        float aw = part.w + r0.w + r1.w + r2.w;

        float cr = (float)(imin(i, 97) - imax(i - 9, 0) + 1);
        float cc = (float)(imin(j, 97) - imax(j - 9, 0) + 1);
        float inv = 1.f / (cr * cc);
        float4 xs = *(const float4*)(xT + base);

        int ch0 = quad*4;
        out[(ch0+0)*IH*IW + p] = xs.x;
        out[(ch0+1)*IH*IW + p] = xs.y;
        out[(ch0+2)*IH*IW + p] = xs.z;
        out[(ch0+3)*IH*IW + p] = xs.w;
        out[(16+ch0+0)*IH*IW + p] = ax*inv - xs.x;
        out[(16+ch0+1)*IH*IW + p] = ay*inv - xs.y;
        out[(16+ch0+2)*IH*IW + p] = az*inv - xs.z;
        out[(16+ch0+3)*IH*IW + p] = aw*inv - xs.w;
    }
}

extern "C" void kernel_launch(void* const* d_in, const int* in_sizes, int n_in,
                              void* d_out, int out_size, void* d_ws, size_t ws_size,
                              hipStream_t stream) {
    const float* x  = (const float*)d_in[0];
    const float* xe = (const float*)d_in[1];
    const float* ye = (const float*)d_in[2];
    float* out = (float*)d_out;
    float* ws  = (float*)d_ws;

    float* dist = ws;
    float* sv   = ws + OFF_SV;
    int*   sd   = (int*)(ws + OFF_SD);
    float* xT   = ws + OFF_XT;
    float* yeP  = ws + OFF_YEP;
    float* xeP  = ws + OFF_XEP;

    {
        int total = XTW*XTW + YEH*YEW + XEH*XEW;
        hipLaunchKernelGGL(k_prep, dim3((total + 255)/256), dim3(256), 0, stream,
                           x, xe, ye, xT, xeP, yeP);
    }

    int base = 0;
    const int nds[3] = {281, 281, 279};
    for (int c = 0; c < 3; ++c) {
        int nd = nds[c];
        hipLaunchKernelGGL(k_dist, dim3(nd*4), dim3(128), 0, stream, xeP, yeP, dist, base);
        int mode = (c == 0 ? 1 : 0) | (c == 2 ? 2 : 0);
        hipLaunchKernelGGL(k_topk, dim3((QN + 63)/64), dim3(256), 0, stream,
                           dist, sv, sd, base, nd, mode);
        base += nd;
    }

    hipLaunchKernelGGL(k_agg, dim3(IH*IW/16), dim3(256), 0, stream, xT, sv, sd, out);
}

// Round 3
// 113.820 us; speedup vs baseline: 2.4130x; 1.4641x over previous
//
#include <hip/hip_runtime.h>

// ---- problem constants ----
#define PS   10
#define KNN  7
#define WSZ  29
#define RR   14
#define IH   96
#define IW   96
#define CH   16
#define CE   8
#define HH   98            // query grid (after pad1)
#define QN   (HH*HH)       // 9604 queries
#define ND   (WSZ*WSZ)     // 841 displacements
#define XTW  124           // padded x-interleaved: coords [-14,109]
#define XTP  14
#define YEW  107
#define YEH  112
#define XEW  144
#define XEH  140
#define QP   9800          // dist plane pitch (98 rows x 100)

// ---- ws layout (float units) ----
#define OFF_SV   8241856ull                        // align64(841*9800)
#define OFF_SD   (OFF_SV + 76832ull)
#define OFF_XT   (OFF_SD + 76832ull)
#define OFF_YEP  (OFF_XT + 246016ull)
#define OFF_XEP  (OFF_YEP + (size_t)(YEH*YEW*CE))
// end ~8.9M floats = 35.6 MB

__device__ __forceinline__ int imin(int a, int b){ return a<b?a:b; }
__device__ __forceinline__ int imax(int a, int b){ return a>b?a:b; }

// ---- K0: pack x -> xT[124][124][16]; ye -> yeP[112][107][8]; xe -> xeP[140][144][8]
__global__ __launch_bounds__(256) void k_prep(const float* __restrict__ x,
                                              const float* __restrict__ xe,
                                              const float* __restrict__ ye,
                                              float* __restrict__ xT,
                                              float* __restrict__ xeP,
                                              float* __restrict__ yeP) {
    int t = blockIdx.x*256 + threadIdx.x;
    if (t < XTW*XTW) {
        int u = t / XTW, v = t % XTW;
        int ui = u - XTP, vi = v - XTP;
        bool inb = ((unsigned)ui < (unsigned)IH) && ((unsigned)vi < (unsigned)IW);
        int off = inb ? (ui*IW + vi) : 0;
        float4* dst = (float4*)(xT + (size_t)t*CH);
        #pragma unroll
        for (int c4 = 0; c4 < 4; ++c4) {
            float4 val;
            val.x = inb ? x[(c4*4+0)*IH*IW + off] : 0.f;
            val.y = inb ? x[(c4*4+1)*IH*IW + off] : 0.f;
            val.z = inb ? x[(c4*4+2)*IH*IW + off] : 0.f;
            val.w = inb ? x[(c4*4+3)*IH*IW + off] : 0.f;
            dst[c4] = val;
        }
        return;
    }
    t -= XTW*XTW;
    if (t < YEH*YEW) {
        int i = t / YEW, j = t % YEW;
        bool inb = ((unsigned)(i-6) < (unsigned)IH) && ((unsigned)(j-6) < (unsigned)IW);
        int off = inb ? ((i-6)*IW + (j-6)) : 0;
        float4* dst = (float4*)(yeP + (size_t)t*CE);
        #pragma unroll
        for (int c4 = 0; c4 < 2; ++c4) {
            float4 val;
            val.x = inb ? ye[(c4*4+0)*IH*IW + off] : 0.f;
            val.y = inb ? ye[(c4*4+1)*IH*IW + off] : 0.f;
            val.z = inb ? ye[(c4*4+2)*IH*IW + off] : 0.f;
            val.w = inb ? ye[(c4*4+3)*IH*IW + off] : 0.f;
            dst[c4] = val;
        }
        return;
    }
    t -= YEH*YEW;
    if (t < XEH*XEW) {
        int i = t / XEW, j = t % XEW;
        bool inb = ((unsigned)(i-20) < (unsigned)IH) && ((unsigned)(j-20) < (unsigned)IW);
        int off = inb ? ((i-20)*IW + (j-20)) : 0;
        float4* dst = (float4*)(xeP + (size_t)t*CE);
        #pragma unroll
        for (int c4 = 0; c4 < 2; ++c4) {
            float4 val;
            val.x = inb ? xe[(c4*4+0)*IH*IW + off] : 0.f;
            val.y = inb ? xe[(c4*4+1)*IH*IW + off] : 0.f;
            val.z = inb ? xe[(c4*4+2)*IH*IW + off] : 0.f;
            val.w = inb ? xe[(c4*4+3)*IH*IW + off] : 0.f;
            dst[c4] = val;
        }
    }
}

// ---- K1: distances. block = (dy, dx-group-of-4, 25-row strip). grid 29*8*4=928
__global__ __launch_bounds__(128) void k_dist(const float* __restrict__ xeP,
                                              const float* __restrict__ yeP,
                                              float* __restrict__ dist) {
    __shared__ float4 xbA[2][110];
    __shared__ float4 xbB[2][110];
    __shared__ float  cs[4*25*109];   // vertical 10-sums, pitch 109

    int b     = blockIdx.x;
    int dy_i  = b >> 5;
    int r5    = b & 31;
    int dxg   = r5 >> 2;
    int strip = r5 & 3;
    int dy    = dy_i - 14;
    int y0s   = strip * 25;
    int t     = threadIdx.x;

    int txc = t < 110 ? t : 109;
    int tyc = t < 107 ? t : 106;
    const float* xptr = xeP + ((size_t)(y0s + dy + 14)*XEW + (txc + dxg*4))*CE;
    const float* yptr = yeP + ((size_t)y0s*YEW + tyc)*CE;
    const size_t xstep = (size_t)XEW*CE, ystep = (size_t)YEW*CE;

    float cum[4] = {0.f,0.f,0.f,0.f};
    float ring[4][10];
    #pragma unroll
    for (int d_ = 0; d_ < 4; ++d_)
        #pragma unroll
        for (int k = 0; k < 10; ++k) ring[d_][k] = 0.f;

    float4 pxa = ((const float4*)xptr)[0], pxb = ((const float4*)xptr)[1];
    float4 pya = ((const float4*)yptr)[0], pyb = ((const float4*)yptr)[1];

#define STEP(S, SLOT) { \
    float4 cxa=pxa, cxb=pxb, cya=pya, cyb=pyb; \
    xptr += xstep; yptr += ystep; \
    pxa = ((const float4*)xptr)[0]; pxb = ((const float4*)xptr)[1]; \
    pya = ((const float4*)yptr)[0]; pyb = ((const float4*)yptr)[1]; \
    if (t < 110) { xbA[(S)&1][t] = cxa; xbB[(S)&1][t] = cxb; } \
    __syncthreads(); \
    if (t < 107) { \
        _Pragma("unroll") \
        for (int dxi = 0; dxi < 4; ++dxi) { \
            float4 xa = xbA[(S)&1][t+dxi]; \
            float4 xb = xbB[(S)&1][t+dxi]; \
            float d0=cya.x-xa.x, d1=cya.y-xa.y, d2=cya.z-xa.z, d3=cya.w-xa.w; \
            float d4=cyb.x-xb.x, d5=cyb.y-xb.y, d6=cyb.z-xb.z, d7=cyb.w-xb.w; \
            float a = d0*d0; a=fmaf(d1,d1,a); a=fmaf(d2,d2,a); a=fmaf(d3,d3,a); \
            a=fmaf(d4,d4,a); a=fmaf(d5,d5,a); a=fmaf(d6,d6,a); a=fmaf(d7,d7,a); \
            float c2 = cum[dxi] + a; cum[dxi] = c2; \
            float outv = c2 - ring[dxi][SLOT]; \
            ring[dxi][SLOT] = c2; \
            if ((S) >= 9) cs[dxi*2725 + ((S)-9)*109 + t] = outv; \
        } \
    } \
}

    for (int sb = 0; sb < 30; sb += 10) {
        #pragma unroll
        for (int sr = 0; sr < 10; ++sr) STEP(sb+sr, sr)
    }
    #pragma unroll
    for (int sr = 0; sr < 4; ++sr) STEP(30+sr, sr)
#undef STEP
    __syncthreads();

    // phase C: horizontal 10-sums, 4 outputs per unit, lane-major over rows
    int nrows = imin(25, 98 - y0s);
    for (int u = t; u < 2500; u += 128) {
        int xg = u / 100;
        int inner = u - xg*100;
        int dxi = inner / 25;
        int r = inner - dxi*25;
        int dxcol = dxg*4 + dxi;
        if (r >= nrows || dxcol >= 29) continue;
        int x0 = xg*4;
        const float* cr = cs + dxi*2725 + r*109 + x0;
        float c0=cr[0],c1=cr[1],c2=cr[2],c3=cr[3],c4=cr[4],c5=cr[5],c6=cr[6],
              c7=cr[7],c8=cr[8],c9=cr[9],c10=cr[10],c11=cr[11],c12=cr[12];
        float s0 = ((c0+c1)+(c2+c3))+((c4+c5)+(c6+c7))+(c8+c9);
        float s1 = s0 - c0 + c10;
        float s2 = s1 - c1 + c11;
        float s3 = s2 - c2 + c12;
        int dx = dxcol - 14;
        int y0 = y0s + r;
        int ni = y0 + dy;
        bool okr = ((unsigned)ni < 98u) && !(dy == 0 && dx == 0);
        float4 o;
        o.x = (okr && (unsigned)(x0+0+dx) < 98u) ? s0 : 1e10f;
        o.y = (okr && (unsigned)(x0+1+dx) < 98u) ? s1 : 1e10f;
        o.z = (okr && (unsigned)(x0+2+dx) < 98u) ? s2 : 1e10f;
        o.w = (okr && (unsigned)(x0+3+dx) < 98u) ? s3 : 1e10f;
        *(float4*)(dist + (size_t)(dy_i*29 + dxcol)*QP + y0*100 + x0) = o;
    }
}

// ---- K2: top-7 over all 841, 8 waves/block, LDS merge, softmax ----
__global__ __launch_bounds__(512) void k_topk(const float* __restrict__ dist,
                                              float* __restrict__ sv, int* __restrict__ sd) {
    __shared__ float lv[7*64*8];
    __shared__ int   lix[7*64*8];
    int wv = threadIdx.x >> 6, ln = threadIdx.x & 63;
    int q = blockIdx.x*64 + ln;
    bool qok = q < QN;
    int qq = qok ? q : 0;
    int y0 = qq / 98, x0 = qq - y0*98;
    int off = y0*100 + x0;

    float ld[KNN]; int li[KNN];
    #pragma unroll
    for (int k = 0; k < KNN; ++k) { ld[k] = 1e30f; li[k] = -1; }

    auto INS = [&](float v, int dsp) {
        float cv = v; int ci = dsp;
        #pragma unroll
        for (int k = 0; k < KNN; ++k) {
            bool sw = cv < ld[k];
            float tf = ld[k]; int ti = li[k];
            ld[k] = sw ? cv : tf;  li[k] = sw ? ci : ti;
            cv    = sw ? tf : cv;  ci    = sw ? ti : ci;
        }
    };

    int s0 = wv*106, s1 = imin(841, s0 + 106);
    #pragma unroll 2
    for (int dd = s0; dd < s1; ++dd)
        INS(dist[(size_t)dd*QP + off], dd);

    if (wv) {
        int bse = ((wv-1)*64 + ln)*8;
        #pragma unroll
        for (int r = 0; r < KNN; ++r) { lv[bse+r] = ld[r]; lix[bse+r] = li[r]; }
    }
    __syncthreads();
    if (wv == 0 && qok) {
        #pragma unroll
        for (int w = 0; w < 7; ++w) {
            int bse = (w*64 + ln)*8;
            #pragma unroll
            for (int r = 0; r < KNN; ++r) INS(lv[bse+r], lix[bse+r]);
        }
        float e[KNN]; float ssum = 0.f;
        #pragma unroll
        for (int r = 0; r < KNN; ++r) { e[r] = __expf(ld[0] - ld[r]); ssum += e[r]; }
        float inv = 1.f / ssum;
        #pragma unroll
        for (int r = 0; r < KNN; ++r) {
            sv[q*8 + r] = e[r] * inv;
            int dsp = li[r];
            int dyk = dsp / WSZ - RR, dxk = dsp % WSZ - RR;
            sd[q*8 + r] = (dyk*XTW + dxk) * CH;    // float-unit delta into xT
        }
    }
}

// ---- K3: aggregation. block = 4x8 pixel tile x 4 quads x 8 (oy,ox)-groups ----
__global__ __launch_bounds__(1024) void k_agg(const float* __restrict__ xT,
                                              const float* __restrict__ wgt,
                                              const int* __restrict__ dlt,
                                              float* __restrict__ out) {
    __shared__ float2 lw[13*17*7];    // (w, delta) per staged query
    __shared__ float4 red[7*128];
    int tid = threadIdx.x;
    int tb = blockIdx.x;
    int ai0 = (tb / 12) * 4, bi0 = (tb % 12) * 8;

    for (int u = tid; u < 13*17*7; u += 1024) {
        int lq = u / 7, k = u - lq*7;
        int lqi = lq / 17, lqj = lq - lqi*17;
        int qi = ai0 - 3 + lqi, qj = bi0 - 3 + lqj;
        bool ok = ((unsigned)qi < 98u) && ((unsigned)qj < 98u);
        int q = ok ? (qi*98 + qj) : 0;
        float w = ok ? wgt[q*8 + k] : 0.f;
        int  dl = ok ? dlt[q*8 + k] : 0;
        lw[u] = make_float2(w, __int_as_float(dl));
    }
    __syncthreads();

    int og   = tid >> 7;          // 0..7
    int rem  = tid & 127;
    int quad = rem & 3;
    int pl   = rem >> 2;          // 0..31
    int py   = pl >> 3, px = pl & 7;
    int ai = ai0 + py, bi = bi0 + px;
    int base = ((ai + XTP)*XTW + (bi + XTP))*CH + quad*4;

    float ax=0.f, ay=0.f, az=0.f, aw=0.f;
    #pragma unroll
    for (int c = 0; c < 13; ++c) {
        int u = og*13 + c;
        if (u >= 100) break;
        int oy = u / 10, ox = u - oy*10;
        int lq = (py + 9 - oy)*17 + (px + 9 - ox);
        const float2* f2p = lw + lq*7;
        #pragma unroll
        for (int k = 0; k < KNN; ++k) {
            float2 wd = f2p[k];
            int dl = __float_as_int(wd.y);
            const float4 xv = *(const float4*)(xT + base + dl);
            ax = fmaf(wd.x, xv.x, ax); ay = fmaf(wd.x, xv.y, ay);
            az = fmaf(wd.x, xv.z, az); aw = fmaf(wd.x, xv.w, aw);
        }
    }

    if (og) { float4 pr; pr.x=ax; pr.y=ay; pr.z=az; pr.w=aw; red[(og-1)*128 + rem] = pr; }
    __syncthreads();
    if (og == 0) {
        #pragma unroll
        for (int w = 0; w < 7; ++w) {
            float4 pr = red[w*128 + rem];
            ax += pr.x; ay += pr.y; az += pr.z; aw += pr.w;
        }
        int i = ai + 6, j = bi + 6;
        float cr = (float)(imin(i, 97) - imax(i - 9, 0) + 1);
        float cc = (float)(imin(j, 97) - imax(j - 9, 0) + 1);
        float inv = 1.f / (cr * cc);
        float4 xs = *(const float4*)(xT + base);
        int p = ai*IW + bi;
        int ch0 = quad*4;
        out[(ch0+0)*IH*IW + p] = xs.x;
        out[(ch0+1)*IH*IW + p] = xs.y;
        out[(ch0+2)*IH*IW + p] = xs.z;
        out[(ch0+3)*IH*IW + p] = xs.w;
        out[(16+ch0+0)*IH*IW + p] = ax*inv - xs.x;
        out[(16+ch0+1)*IH*IW + p] = ay*inv - xs.y;
        out[(16+ch0+2)*IH*IW + p] = az*inv - xs.z;
        out[(16+ch0+3)*IH*IW + p] = aw*inv - xs.w;
    }
}

extern "C" void kernel_launch(void* const* d_in, const int* in_sizes, int n_in,
                              void* d_out, int out_size, void* d_ws, size_t ws_size,
                              hipStream_t stream) {
    const float* x  = (const float*)d_in[0];
    const float* xe = (const float*)d_in[1];
    const float* ye = (const float*)d_in[2];
    float* out = (float*)d_out;
    float* ws  = (float*)d_ws;

    float* dist = ws;
    float* sv   = ws + OFF_SV;
    int*   sd   = (int*)(ws + OFF_SD);
    float* xT   = ws + OFF_XT;
    float* yeP  = ws + OFF_YEP;
    float* xeP  = ws + OFF_XEP;

    {
        int total = XTW*XTW + YEH*YEW + XEH*XEW;
        hipLaunchKernelGGL(k_prep, dim3((total + 255)/256), dim3(256), 0, stream,
                           x, xe, ye, xT, xeP, yeP);
    }
    hipLaunchKernelGGL(k_dist, dim3(29*8*4), dim3(128), 0, stream, xeP, yeP, dist);
    hipLaunchKernelGGL(k_topk, dim3((QN + 63)/64), dim3(512), 0, stream, dist, sv, sd);
    hipLaunchKernelGGL(k_agg,  dim3(24*12), dim3(1024), 0, stream, xT, sv, sd, out);
}

// Round 4
// 93.918 us; speedup vs baseline: 2.9243x; 1.2119x over previous
//
#include <hip/hip_runtime.h>

// ---- problem constants ----
#define PS   10
#define KNN  7
#define WSZ  29
#define RR   14
#define IH   96
#define IW   96
#define CH   16
#define CE   8
#define HH   98            // query grid (after pad1)
#define QN   (HH*HH)       // 9604 queries
#define ND   (WSZ*WSZ)     // 841 displacements
#define XTW  124           // padded x-interleaved: coords [-14,109]
#define XTP  14
#define YEW  107
#define YEH  112
#define XEW  144
#define XEH  140
#define QP   9800          // dist plane pitch (98 rows x 100)

#define DROWS 14           // k_dist strip rows
#define DSTEPS (DROWS+9)   // 23
#define CSP  136           // cs row pitch (swizzled, max offset 135)

// ---- ws layout (float units) ----
#define OFF_SV   8241856ull                        // align64(841*9800)
#define OFF_SD   (OFF_SV + 76832ull)
#define OFF_XT   (OFF_SD + 76832ull)
#define OFF_YEP  (OFF_XT + 246016ull)
#define OFF_XEP  (OFF_YEP + (size_t)(YEH*YEW*CE))
// end ~8.9M floats = 35.6 MB

__device__ __forceinline__ int imin(int a, int b){ return a<b?a:b; }
__device__ __forceinline__ int imax(int a, int b){ return a>b?a:b; }

// ---- K0: pack x -> xT[124][124][16]; ye -> yeP[112][107][8]; xe -> xeP[140][144][8]
__global__ __launch_bounds__(256) void k_prep(const float* __restrict__ x,
                                              const float* __restrict__ xe,
                                              const float* __restrict__ ye,
                                              float* __restrict__ xT,
                                              float* __restrict__ xeP,
                                              float* __restrict__ yeP) {
    int t = blockIdx.x*256 + threadIdx.x;
    if (t < XTW*XTW) {
        int u = t / XTW, v = t % XTW;
        int ui = u - XTP, vi = v - XTP;
        bool inb = ((unsigned)ui < (unsigned)IH) && ((unsigned)vi < (unsigned)IW);
        int off = inb ? (ui*IW + vi) : 0;
        float4* dst = (float4*)(xT + (size_t)t*CH);
        #pragma unroll
        for (int c4 = 0; c4 < 4; ++c4) {
            float4 val;
            val.x = inb ? x[(c4*4+0)*IH*IW + off] : 0.f;
            val.y = inb ? x[(c4*4+1)*IH*IW + off] : 0.f;
            val.z = inb ? x[(c4*4+2)*IH*IW + off] : 0.f;
            val.w = inb ? x[(c4*4+3)*IH*IW + off] : 0.f;
            dst[c4] = val;
        }
        return;
    }
    t -= XTW*XTW;
    if (t < YEH*YEW) {
        int i = t / YEW, j = t % YEW;
        bool inb = ((unsigned)(i-6) < (unsigned)IH) && ((unsigned)(j-6) < (unsigned)IW);
        int off = inb ? ((i-6)*IW + (j-6)) : 0;
        float4* dst = (float4*)(yeP + (size_t)t*CE);
        #pragma unroll
        for (int c4 = 0; c4 < 2; ++c4) {
            float4 val;
            val.x = inb ? ye[(c4*4+0)*IH*IW + off] : 0.f;
            val.y = inb ? ye[(c4*4+1)*IH*IW + off] : 0.f;
            val.z = inb ? ye[(c4*4+2)*IH*IW + off] : 0.f;
            val.w = inb ? ye[(c4*4+3)*IH*IW + off] : 0.f;
            dst[c4] = val;
        }
        return;
    }
    t -= YEH*YEW;
    if (t < XEH*XEW) {
        int i = t / XEW, j = t % XEW;
        bool inb = ((unsigned)(i-20) < (unsigned)IH) && ((unsigned)(j-20) < (unsigned)IW);
        int off = inb ? ((i-20)*IW + (j-20)) : 0;
        float4* dst = (float4*)(xeP + (size_t)t*CE);
        #pragma unroll
        for (int c4 = 0; c4 < 2; ++c4) {
            float4 val;
            val.x = inb ? xe[(c4*4+0)*IH*IW + off] : 0.f;
            val.y = inb ? xe[(c4*4+1)*IH*IW + off] : 0.f;
            val.z = inb ? xe[(c4*4+2)*IH*IW + off] : 0.f;
            val.w = inb ? xe[(c4*4+3)*IH*IW + off] : 0.f;
            dst[c4] = val;
        }
    }
}

// ---- K1: distances, dy-sharing register-pipeline design ----
// block = (dy-group of 4, dx, 14-row strip). grid = 8*29*7 = 1624, 128 thr.
// Lane owns one query column; x rows stream via 4-slot reg ring (loaded once,
// shared across 4 dy); vertical 10-window via 10-slot reg ring; LDS only for
// the horizontal pass with odd-stride (col + col/4) swizzle -> conflict-free.
__global__ __launch_bounds__(128) void k_dist(const float* __restrict__ xeP,
                                              const float* __restrict__ yeP,
                                              float* __restrict__ dist) {
    __shared__ float cs[4*DROWS*CSP];      // 30.5 KB

    int b     = blockIdx.x;
    int dx_i  = b % 29;
    int rem   = b / 29;
    int strip = rem % 7;
    int dyg   = rem / 7;                   // 0..7 (group 7 = dy_i 28 only)
    int y0s   = strip * DROWS;
    int t     = threadIdx.x;
    int tc    = t < 107 ? t : 106;

    const size_t xstep = (size_t)XEW*CE, ystep = (size_t)YEW*CE;
    const float* xload = xeP + ((size_t)(y0s + dyg*4)*XEW + (tc + dx_i))*CE;
    const float* yload = yeP + ((size_t)y0s*YEW + tc)*CE;

    float4 xr[4][2];
    #pragma unroll
    for (int r = 0; r < 3; ++r) {
        xr[r][0] = ((const float4*)xload)[0];
        xr[r][1] = ((const float4*)xload)[1];
        xload += xstep;
    }
    float wsum[4] = {0.f,0.f,0.f,0.f};
    float hist[4][10];

    bool act = t < 107;
    #pragma unroll
    for (int s = 0; s < DSTEPS; ++s) {
        float4 xna = ((const float4*)xload)[0];
        float4 xnb = ((const float4*)xload)[1];
        xload += xstep;
        float4 ya = ((const float4*)yload)[0];
        float4 yb = ((const float4*)yload)[1];
        yload += ystep;
        xr[(s+3)&3][0] = xna;
        xr[(s+3)&3][1] = xnb;
        #pragma unroll
        for (int dyi = 0; dyi < 4; ++dyi) {
            float4 xa = xr[(s+dyi)&3][0];
            float4 xb = xr[(s+dyi)&3][1];
            float d0=ya.x-xa.x, d1=ya.y-xa.y, d2=ya.z-xa.z, d3=ya.w-xa.w;
            float d4=yb.x-xb.x, d5=yb.y-xb.y, d6=yb.z-xb.z, d7=yb.w-xb.w;
            float a = d0*d0;
            a=fmaf(d1,d1,a); a=fmaf(d2,d2,a); a=fmaf(d3,d3,a);
            a=fmaf(d4,d4,a); a=fmaf(d5,d5,a); a=fmaf(d6,d6,a);
            a=fmaf(d7,d7,a);
            float w = wsum[dyi];
            if (s >= 10) w -= hist[dyi][s%10];
            w += a;
            wsum[dyi] = w;
            hist[dyi][s%10] = a;
            if (s >= 9 && act)
                cs[dyi*(DROWS*CSP) + (s-9)*CSP + tc + (tc>>2)] = w;
        }
    }
    __syncthreads();

    // horizontal 10-sums: 4 dyi x 14 rows x 25 col-groups = 1400 units
    for (int u = t; u < 4*DROWS*25; u += 128) {
        int cg  = u % 25;
        int rr  = u / 25;
        int r   = rr % DROWS;
        int dyi = rr / DROWS;
        int dy_i = dyg*4 + dyi;
        if (dy_i > 28) continue;
        const float* bse = cs + dyi*(DROWS*CSP) + r*CSP + 5*cg;
        float v0=bse[0], v1=bse[1], v2=bse[2], v3=bse[3];
        float v5=bse[5], v6=bse[6], v7=bse[7], v8=bse[8];
        float v10=bse[10], v11=bse[11], v12=bse[12], v13=bse[13], v15=bse[15];
        float s0 = ((v0+v1)+(v2+v3)) + ((v5+v6)+(v7+v8)) + (v10+v11);
        float s1 = s0 - v0 + v12;
        float s2 = s1 - v1 + v13;
        float s3 = s2 - v2 + v15;
        int y0 = y0s + r;
        int dy = dy_i - 14, dx = dx_i - 14;
        int ni = y0 + dy;
        bool okr = ((unsigned)ni < 98u) && !(dy == 0 && dx == 0);
        int x0 = 4*cg;
        float4 o;
        o.x = (okr && (unsigned)(x0+0+dx) < 98u) ? s0 : 1e10f;
        o.y = (okr && (unsigned)(x0+1+dx) < 98u) ? s1 : 1e10f;
        o.z = (okr && (unsigned)(x0+2+dx) < 98u) ? s2 : 1e10f;
        o.w = (okr && (unsigned)(x0+3+dx) < 98u) ? s3 : 1e10f;
        *(float4*)(dist + (size_t)(dy_i*29 + dx_i)*QP + y0*100 + x0) = o;
    }
}

// ---- K2: top-7 over all 841, 8 waves/block, LDS merge, softmax ----
__global__ __launch_bounds__(512) void k_topk(const float* __restrict__ dist,
                                              float* __restrict__ sv, int* __restrict__ sd) {
    __shared__ float lv[7*64*8];
    __shared__ int   lix[7*64*8];
    int wv = threadIdx.x >> 6, ln = threadIdx.x & 63;
    int q = blockIdx.x*64 + ln;
    bool qok = q < QN;
    int qq = qok ? q : 0;
    int y0 = qq / 98, x0 = qq - y0*98;
    int off = y0*100 + x0;

    float ld[KNN]; int li[KNN];
    #pragma unroll
    for (int k = 0; k < KNN; ++k) { ld[k] = 1e30f; li[k] = -1; }

    auto INS = [&](float v, int dsp) {
        float cv = v; int ci = dsp;
        #pragma unroll
        for (int k = 0; k < KNN; ++k) {
            bool sw = cv < ld[k];
            float tf = ld[k]; int ti = li[k];
            ld[k] = sw ? cv : tf;  li[k] = sw ? ci : ti;
            cv    = sw ? tf : cv;  ci    = sw ? ti : ci;
        }
    };

    int s0 = wv*106, s1 = imin(841, s0 + 106);
    #pragma unroll 2
    for (int dd = s0; dd < s1; ++dd)
        INS(dist[(size_t)dd*QP + off], dd);

    if (wv) {
        int bse = ((wv-1)*64 + ln)*8;
        #pragma unroll
        for (int r = 0; r < KNN; ++r) { lv[bse+r] = ld[r]; lix[bse+r] = li[r]; }
    }
    __syncthreads();
    if (wv == 0 && qok) {
        #pragma unroll
        for (int w = 0; w < 7; ++w) {
            int bse = (w*64 + ln)*8;
            #pragma unroll
            for (int r = 0; r < KNN; ++r) INS(lv[bse+r], lix[bse+r]);
        }
        float e[KNN]; float ssum = 0.f;
        #pragma unroll
        for (int r = 0; r < KNN; ++r) { e[r] = __expf(ld[0] - ld[r]); ssum += e[r]; }
        float inv = 1.f / ssum;
        #pragma unroll
        for (int r = 0; r < KNN; ++r) {
            sv[q*8 + r] = e[r] * inv;
            int dsp = li[r];
            int dyk = dsp / WSZ - RR, dxk = dsp % WSZ - RR;
            sd[q*8 + r] = (dyk*XTW + dxk) * CH;    // float-unit delta into xT
        }
    }
}

// ---- K3: aggregation. block = 4x8 pixel tile x 4 quads x 8 (oy,ox)-groups ----
__global__ __launch_bounds__(1024) void k_agg(const float* __restrict__ xT,
                                              const float* __restrict__ wgt,
                                              const int* __restrict__ dlt,
                                              float* __restrict__ out) {
    __shared__ float2 lw[13*17*7];    // (w, delta) per staged query
    __shared__ float4 red[7*128];
    int tid = threadIdx.x;
    int tb = blockIdx.x;
    int ai0 = (tb / 12) * 4, bi0 = (tb % 12) * 8;

    for (int u = tid; u < 13*17*7; u += 1024) {
        int lq = u / 7, k = u - lq*7;
        int lqi = lq / 17, lqj = lq - lqi*17;
        int qi = ai0 - 3 + lqi, qj = bi0 - 3 + lqj;
        bool ok = ((unsigned)qi < 98u) && ((unsigned)qj < 98u);
        int q = ok ? (qi*98 + qj) : 0;
        float w = ok ? wgt[q*8 + k] : 0.f;
        int  dl = ok ? dlt[q*8 + k] : 0;
        lw[u] = make_float2(w, __int_as_float(dl));
    }
    __syncthreads();

    int og   = tid >> 7;          // 0..7
    int rem  = tid & 127;
    int quad = rem & 3;
    int pl   = rem >> 2;          // 0..31
    int py   = pl >> 3, px = pl & 7;
    int ai = ai0 + py, bi = bi0 + px;
    int base = ((ai + XTP)*XTW + (bi + XTP))*CH + quad*4;

    float ax=0.f, ay=0.f, az=0.f, aw=0.f;
    #pragma unroll
    for (int c = 0; c < 13; ++c) {
        int u = og*13 + c;
        if (u >= 100) break;
        int oy = u / 10, ox = u - oy*10;
        int lq = (py + 9 - oy)*17 + (px + 9 - ox);
        const float2* f2p = lw + lq*7;
        #pragma unroll
        for (int k = 0; k < KNN; ++k) {
            float2 wd = f2p[k];
            int dl = __float_as_int(wd.y);
            const float4 xv = *(const float4*)(xT + base + dl);
            ax = fmaf(wd.x, xv.x, ax); ay = fmaf(wd.x, xv.y, ay);
            az = fmaf(wd.x, xv.z, az); aw = fmaf(wd.x, xv.w, aw);
        }
    }

    if (og) { float4 pr; pr.x=ax; pr.y=ay; pr.z=az; pr.w=aw; red[(og-1)*128 + rem] = pr; }
    __syncthreads();
    if (og == 0) {
        #pragma unroll
        for (int w = 0; w < 7; ++w) {
            float4 pr = red[w*128 + rem];
            ax += pr.x; ay += pr.y; az += pr.z; aw += pr.w;
        }
        int i = ai + 6, j = bi + 6;
        float cr = (float)(imin(i, 97) - imax(i - 9, 0) + 1);
        float cc = (float)(imin(j, 97) - imax(j - 9, 0) + 1);
        float inv = 1.f / (cr * cc);
        float4 xs = *(const float4*)(xT + base);
        int p = ai*IW + bi;
        int ch0 = quad*4;
        out[(ch0+0)*IH*IW + p] = xs.x;
        out[(ch0+1)*IH*IW + p] = xs.y;
        out[(ch0+2)*IH*IW + p] = xs.z;
        out[(ch0+3)*IH*IW + p] = xs.w;
        out[(16+ch0+0)*IH*IW + p] = ax*inv - xs.x;
        out[(16+ch0+1)*IH*IW + p] = ay*inv - xs.y;
        out[(16+ch0+2)*IH*IW + p] = az*inv - xs.z;
        out[(16+ch0+3)*IH*IW + p] = aw*inv - xs.w;
    }
}

extern "C" void kernel_launch(void* const* d_in, const int* in_sizes, int n_in,
                              void* d_out, int out_size, void* d_ws, size_t ws_size,
                              hipStream_t stream) {
    const float* x  = (const float*)d_in[0];
    const float* xe = (const float*)d_in[1];
    const float* ye = (const float*)d_in[2];
    float* out = (float*)d_out;
    float* ws  = (float*)d_ws;

    float* dist = ws;
    float* sv   = ws + OFF_SV;
    int*   sd   = (int*)(ws + OFF_SD);
    float* xT   = ws + OFF_XT;
    float* yeP  = ws + OFF_YEP;
    float* xeP  = ws + OFF_XEP;

    {
        int total = XTW*XTW + YEH*YEW + XEH*XEW;
        hipLaunchKernelGGL(k_prep, dim3((total + 255)/256), dim3(256), 0, stream,
                           x, xe, ye, xT, xeP, yeP);
    }
    hipLaunchKernelGGL(k_dist, dim3(8*29*7), dim3(128), 0, stream, xeP, yeP, dist);
    hipLaunchKernelGGL(k_topk, dim3((QN + 63)/64), dim3(512), 0, stream, dist, sv, sd);
    hipLaunchKernelGGL(k_agg,  dim3(24*12), dim3(1024), 0, stream, xT, sv, sd, out);
}

// Round 5
// 79.116 us; speedup vs baseline: 3.4715x; 1.1871x over previous
//
#include <hip/hip_runtime.h>

// ---- problem constants ----
#define PS   10
#define KNN  7
#define WSZ  29
#define RR   14
#define IH   96
#define IW   96
#define CH   16
#define CE   8
#define HH   98            // query grid (after pad1)
#define QN   (HH*HH)       // 9604 queries
#define ND   (WSZ*WSZ)     // 841 displacements
#define XTW  124           // padded x-interleaved: coords [-14,109]
#define XTP  14
#define YEW  107
#define YEH  112
#define XEW  144
#define XEH  140
#define QP   9800          // dist plane pitch (98 rows x 100)

// ---- ws layout (float units) ----
#define OFF_SV   8241856ull                 // align64(841*9800)
#define OFF_SD   (OFF_SV + 76832ull)
#define OFF_CV   (OFF_SD + 76832ull)        // stage-A candidates: QN*4*8
#define OFF_CI   (OFF_CV + 307328ull)
#define OFF_XT   (OFF_CI + 307328ull)
#define OFF_YEP  (OFF_XT + 246016ull)
#define OFF_XEP  (OFF_YEP + 95872ull)
// end = OFF_XEP + 161280 = 9,513,344 floats = 38.1 MB

__device__ __forceinline__ int imin(int a, int b){ return a<b?a:b; }
__device__ __forceinline__ int imax(int a, int b){ return a>b?a:b; }

// ---- K0: pack x -> xT[124][124][16]; ye -> yeP[112][107][8]; xe -> xeP[140][144][8]
__global__ __launch_bounds__(256) void k_prep(const float* __restrict__ x,
                                              const float* __restrict__ xe,
                                              const float* __restrict__ ye,
                                              float* __restrict__ xT,
                                              float* __restrict__ xeP,
                                              float* __restrict__ yeP) {
    int t = blockIdx.x*256 + threadIdx.x;
    if (t < XTW*XTW) {
        int u = t / XTW, v = t % XTW;
        int ui = u - XTP, vi = v - XTP;
        bool inb = ((unsigned)ui < (unsigned)IH) && ((unsigned)vi < (unsigned)IW);
        int off = inb ? (ui*IW + vi) : 0;
        float4* dst = (float4*)(xT + (size_t)t*CH);
        #pragma unroll
        for (int c4 = 0; c4 < 4; ++c4) {
            float4 val;
            val.x = inb ? x[(c4*4+0)*IH*IW + off] : 0.f;
            val.y = inb ? x[(c4*4+1)*IH*IW + off] : 0.f;
            val.z = inb ? x[(c4*4+2)*IH*IW + off] : 0.f;
            val.w = inb ? x[(c4*4+3)*IH*IW + off] : 0.f;
            dst[c4] = val;
        }
        return;
    }
    t -= XTW*XTW;
    if (t < YEH*YEW) {
        int i = t / YEW, j = t % YEW;
        bool inb = ((unsigned)(i-6) < (unsigned)IH) && ((unsigned)(j-6) < (unsigned)IW);
        int off = inb ? ((i-6)*IW + (j-6)) : 0;
        float4* dst = (float4*)(yeP + (size_t)t*CE);
        #pragma unroll
        for (int c4 = 0; c4 < 2; ++c4) {
            float4 val;
            val.x = inb ? ye[(c4*4+0)*IH*IW + off] : 0.f;
            val.y = inb ? ye[(c4*4+1)*IH*IW + off] : 0.f;
            val.z = inb ? ye[(c4*4+2)*IH*IW + off] : 0.f;
            val.w = inb ? ye[(c4*4+3)*IH*IW + off] : 0.f;
            dst[c4] = val;
        }
        return;
    }
    t -= YEH*YEW;
    if (t < XEH*XEW) {
        int i = t / XEW, j = t % XEW;
        bool inb = ((unsigned)(i-20) < (unsigned)IH) && ((unsigned)(j-20) < (unsigned)IW);
        int off = inb ? ((i-20)*IW + (j-20)) : 0;
        float4* dst = (float4*)(xeP + (size_t)t*CE);
        #pragma unroll
        for (int c4 = 0; c4 < 2; ++c4) {
            float4 val;
            val.x = inb ? xe[(c4*4+0)*IH*IW + off] : 0.f;
            val.y = inb ? xe[(c4*4+1)*IH*IW + off] : 0.f;
            val.z = inb ? xe[(c4*4+2)*IH*IW + off] : 0.f;
            val.w = inb ? xe[(c4*4+3)*IH*IW + off] : 0.f;
            dst[c4] = val;
        }
    }
}

// ---- K1: distances, streaming phase-C with 3-row LDS ring (6.4 KB) ----
// block = (dy-group of 4, dx, 14-row strip). grid = 8*29*7 = 1624, 128 thr.
__global__ __launch_bounds__(128, 4) void k_dist(const float* __restrict__ xeP,
                                                 const float* __restrict__ yeP,
                                                 float* __restrict__ dist) {
    __shared__ float ring[3][544];       // 3 slots x 4 dyi x 136 (swizzled)

    int b     = blockIdx.x;
    int dx_i  = b % 29;
    int rem   = b / 29;
    int strip = rem % 7;
    int dyg   = rem / 7;                 // 0..7
    int y0s   = strip * 14;
    int t     = threadIdx.x;
    int tc    = t < 107 ? t : 106;
    int csw   = tc + (tc >> 2);          // swizzled col (stride-5 per 4 cols)
    bool wact = t < 107;

    // phase-C unit (threads 0..99): 4 dyi x 25 col-groups
    int dyi_u = t / 25;
    int cg_u  = t - dyi_u*25;
    int dy_u  = dyg*4 + dyi_u - 14;
    bool plane_ok = (t < 100) && (dyg*4 + dyi_u <= 28);
    int dx    = dx_i - 14;
    bool selfd = (dy_u == 0) && (dx == 0);
    int x0u   = 4*cg_u;
    const float* rbp = &ring[0][0] + dyi_u*136 + 5*cg_u;
    float* dout = dist + (size_t)((dyg*4 + dyi_u)*29 + dx_i)*QP + x0u;

    const size_t xstep = (size_t)XEW*CE, ystep = (size_t)YEW*CE;
    const float* xload = xeP + ((size_t)(y0s + dyg*4)*XEW + (tc + dx_i))*CE;
    const float* yload = yeP + ((size_t)y0s*YEW + tc)*CE;

    float4 xr[4][2];
    #pragma unroll
    for (int r = 0; r < 3; ++r) {
        xr[r][0] = ((const float4*)xload)[0];
        xr[r][1] = ((const float4*)xload)[1];
        xload += xstep;
    }
    float wsum[4] = {0.f,0.f,0.f,0.f};
    float hist[4][10];

#define DSTEP(S) { \
    float4 xna = ((const float4*)xload)[0]; \
    float4 xnb = ((const float4*)xload)[1]; \
    xload += xstep; \
    float4 ya  = ((const float4*)yload)[0]; \
    float4 yb  = ((const float4*)yload)[1]; \
    yload += ystep; \
    xr[((S)+3)&3][0] = xna; xr[((S)+3)&3][1] = xnb; \
    _Pragma("unroll") \
    for (int dyi = 0; dyi < 4; ++dyi) { \
        float4 xa = xr[((S)+dyi)&3][0]; \
        float4 xb = xr[((S)+dyi)&3][1]; \
        float d0=ya.x-xa.x, d1=ya.y-xa.y, d2=ya.z-xa.z, d3=ya.w-xa.w; \
        float d4=yb.x-xb.x, d5=yb.y-xb.y, d6=yb.z-xb.z, d7=yb.w-xb.w; \
        float a = d0*d0; \
        a=fmaf(d1,d1,a); a=fmaf(d2,d2,a); a=fmaf(d3,d3,a); \
        a=fmaf(d4,d4,a); a=fmaf(d5,d5,a); a=fmaf(d6,d6,a); \
        a=fmaf(d7,d7,a); \
        float w = wsum[dyi] + a; \
        if ((S) >= 10) w -= hist[dyi][(S)%10]; \
        wsum[dyi] = w; \
        hist[dyi][(S)%10] = a; \
        if ((S) >= 9 && wact) ring[(S)%3][dyi*136 + csw] = w; \
    } \
    __syncthreads(); \
    if ((S) >= 9 && plane_ok) { \
        const float* bse = rbp + ((S)%3)*544; \
        float v0=bse[0],v1=bse[1],v2=bse[2],v3=bse[3]; \
        float v5=bse[5],v6=bse[6],v7=bse[7],v8=bse[8]; \
        float v10=bse[10],v11=bse[11],v12=bse[12],v13=bse[13],v15=bse[15]; \
        float s0 = ((v0+v1)+(v2+v3)) + ((v5+v6)+(v7+v8)) + (v10+v11); \
        float s1 = s0 - v0 + v12; \
        float s2 = s1 - v1 + v13; \
        float s3 = s2 - v2 + v15; \
        int y0 = y0s + (S) - 9; \
        int ni = y0 + dy_u; \
        bool okr = ((unsigned)ni < 98u) && !selfd; \
        float4 o; \
        o.x = (okr && (unsigned)(x0u+0+dx) < 98u) ? s0 : 1e10f; \
        o.y = (okr && (unsigned)(x0u+1+dx) < 98u) ? s1 : 1e10f; \
        o.z = (okr && (unsigned)(x0u+2+dx) < 98u) ? s2 : 1e10f; \
        o.w = (okr && (unsigned)(x0u+3+dx) < 98u) ? s3 : 1e10f; \
        *(float4*)(dout + y0*100) = o; \
    } \
}

    DSTEP(0)  DSTEP(1)  DSTEP(2)  DSTEP(3)  DSTEP(4)
    DSTEP(5)  DSTEP(6)  DSTEP(7)  DSTEP(8)  DSTEP(9)
    DSTEP(10) DSTEP(11) DSTEP(12) DSTEP(13) DSTEP(14)
    DSTEP(15) DSTEP(16) DSTEP(17) DSTEP(18) DSTEP(19)
    DSTEP(20) DSTEP(21) DSTEP(22)
#undef DSTEP
}

// ---- K2a: stage-A top-7 per (query, displacement-quarter). grid 151*4 ----
__global__ __launch_bounds__(256) void k_topkA(const float* __restrict__ dist,
                                               float* __restrict__ cv, int* __restrict__ ci) {
    __shared__ float lv[3*64*8];
    __shared__ int   lix[3*64*8];
    int wv = threadIdx.x >> 6, ln = threadIdx.x & 63;
    int qb = blockIdx.x % 151;
    int rg = blockIdx.x / 151;           // 0..3
    int q  = qb*64 + ln;
    int qq = q < QN ? q : QN-1;
    int y0 = qq / 98, x0 = qq - y0*98;
    int off = y0*100 + x0;

    int rbase = rg*210 + (rg > 0 ? 1 : 0);   // 0,211,421,631
    int ndr   = (rg == 0) ? 211 : 210;
    int s0 = rbase + wv*53;
    int s1 = imin(rbase + ndr, s0 + 53);

    float ld[KNN]; int li[KNN];
    #pragma unroll
    for (int k = 0; k < KNN; ++k) { ld[k] = 1e30f; li[k] = -1; }

    auto INS = [&](float v, int dsp) {
        float cvv = v; int cii = dsp;
        #pragma unroll
        for (int k = 0; k < KNN; ++k) {
            bool sw = cvv < ld[k];
            float tf = ld[k]; int ti = li[k];
            ld[k] = sw ? cvv : tf;  li[k] = sw ? cii : ti;
            cvv   = sw ? tf : cvv;  cii   = sw ? ti : cii;
        }
    };

    #pragma unroll 2
    for (int dd = s0; dd < s1; ++dd)
        INS(dist[(size_t)dd*QP + off], dd);

    if (wv) {
        int bse = ((wv-1)*64 + ln)*8;
        #pragma unroll
        for (int r = 0; r < KNN; ++r) { lv[bse+r] = ld[r]; lix[bse+r] = li[r]; }
    }
    __syncthreads();
    if (wv == 0 && q < QN) {
        #pragma unroll
        for (int w = 0; w < 3; ++w) {
            int bse = (w*64 + ln)*8;
            #pragma unroll
            for (int r = 0; r < KNN; ++r) INS(lv[bse+r], lix[bse+r]);
        }
        #pragma unroll
        for (int r = 0; r < KNN; ++r) {
            cv[(q*4 + rg)*8 + r] = ld[r];
            ci[(q*4 + rg)*8 + r] = li[r];
        }
    }
}

// ---- K2b: merge 28 candidates per query, softmax, delta conversion ----
__global__ __launch_bounds__(256) void k_topkB(const float* __restrict__ cv,
                                               const int* __restrict__ ci,
                                               float* __restrict__ sv, int* __restrict__ sd) {
    int q = blockIdx.x*256 + threadIdx.x;
    if (q >= QN) return;

    float ld[KNN]; int li[KNN];
    #pragma unroll
    for (int k = 0; k < KNN; ++k) { ld[k] = 1e30f; li[k] = -1; }

    auto INS = [&](float v, int dsp) {
        float cvv = v; int cii = dsp;
        #pragma unroll
        for (int k = 0; k < KNN; ++k) {
            bool sw = cvv < ld[k];
            float tf = ld[k]; int ti = li[k];
            ld[k] = sw ? cvv : tf;  li[k] = sw ? cii : ti;
            cvv   = sw ? tf : cvv;  cii   = sw ? ti : cii;
        }
    };

    #pragma unroll
    for (int rg = 0; rg < 4; ++rg) {
        #pragma unroll
        for (int r = 0; r < KNN; ++r)
            INS(cv[(q*4 + rg)*8 + r], ci[(q*4 + rg)*8 + r]);
    }

    float e[KNN]; float ssum = 0.f;
    #pragma unroll
    for (int r = 0; r < KNN; ++r) { e[r] = __expf(ld[0] - ld[r]); ssum += e[r]; }
    float inv = 1.f / ssum;
    #pragma unroll
    for (int r = 0; r < KNN; ++r) {
        sv[q*8 + r] = e[r] * inv;
        int dsp = li[r];
        int dyk = dsp / WSZ - RR, dxk = dsp % WSZ - RR;
        sd[q*8 + r] = (dyk*XTW + dxk) * CH;    // float-unit delta into xT
    }
}

// ---- K3: aggregation. block = 4x4 pixel tile x 4 quads x 8 (oy,ox)-groups ----
__global__ __launch_bounds__(512) void k_agg(const float* __restrict__ xT,
                                             const float* __restrict__ wgt,
                                             const int* __restrict__ dlt,
                                             float* __restrict__ out) {
    __shared__ float2 lw[13*13*7];    // 9.5 KB staged (w, delta)
    __shared__ float4 red[7*64];      // 7 KB
    int tid = threadIdx.x;
    int tb = blockIdx.x;
    int ai0 = (tb / 24) * 4, bi0 = (tb % 24) * 4;

    for (int u = tid; u < 13*13*7; u += 512) {
        int lq = u / 7, k = u - lq*7;
        int lqi = lq / 13, lqj = lq - lqi*13;
        int qi = ai0 - 3 + lqi, qj = bi0 - 3 + lqj;
        bool ok = ((unsigned)qi < 98u) && ((unsigned)qj < 98u);
        int q = ok ? (qi*98 + qj) : 0;
        float w = ok ? wgt[q*8 + k] : 0.f;
        int  dl = ok ? dlt[q*8 + k] : 0;
        lw[u] = make_float2(w, __int_as_float(dl));
    }
    __syncthreads();

    int og   = tid >> 6;          // 0..7
    int rem  = tid & 63;
    int quad = rem & 3;
    int pl   = rem >> 2;          // 0..15
    int py   = pl >> 2, px = pl & 3;
    int ai = ai0 + py, bi = bi0 + px;
    int base = ((ai + XTP)*XTW + (bi + XTP))*CH + quad*4;

    float ax=0.f, ay=0.f, az=0.f, aw=0.f;
    #pragma unroll
    for (int c = 0; c < 13; ++c) {
        int u = og*13 + c;
        if (u >= 100) break;
        int oy = u / 10, ox = u - oy*10;
        int lq = (py + 9 - oy)*13 + (px + 9 - ox);
        const float2* f2p = lw + lq*7;
        #pragma unroll
        for (int k = 0; k < KNN; ++k) {
            float2 wd = f2p[k];
            int dl = __float_as_int(wd.y);
            const float4 xv = *(const float4*)(xT + base + dl);
            ax = fmaf(wd.x, xv.x, ax); ay = fmaf(wd.x, xv.y, ay);
            az = fmaf(wd.x, xv.z, az); aw = fmaf(wd.x, xv.w, aw);
        }
    }

    if (og) {
        float4 pr; pr.x=ax; pr.y=ay; pr.z=az; pr.w=aw;
        red[(og-1)*64 + rem] = pr;
    }
    __syncthreads();
    if (og == 0) {
        #pragma unroll
        for (int w = 0; w < 7; ++w) {
            float4 pr = red[w*64 + rem];
            ax += pr.x; ay += pr.y; az += pr.z; aw += pr.w;
        }
        int i = ai + 6, j = bi + 6;
        float cr = (float)(imin(i, 97) - imax(i - 9, 0) + 1);
        float cc = (float)(imin(j, 97) - imax(j - 9, 0) + 1);
        float inv = 1.f / (cr * cc);
        float4 xs = *(const float4*)(xT + base);
        int p = ai*IW + bi;
        int ch0 = quad*4;
        out[(ch0+0)*IH*IW + p] = xs.x;
        out[(ch0+1)*IH*IW + p] = xs.y;
        out[(ch0+2)*IH*IW + p] = xs.z;
        out[(ch0+3)*IH*IW + p] = xs.w;
        out[(16+ch0+0)*IH*IW + p] = ax*inv - xs.x;
        out[(16+ch0+1)*IH*IW + p] = ay*inv - xs.y;
        out[(16+ch0+2)*IH*IW + p] = az*inv - xs.z;
        out[(16+ch0+3)*IH*IW + p] = aw*inv - xs.w;
    }
}

extern "C" void kernel_launch(void* const* d_in, const int* in_sizes, int n_in,
                              void* d_out, int out_size, void* d_ws, size_t ws_size,
                              hipStream_t stream) {
    const float* x  = (const float*)d_in[0];
    const float* xe = (const float*)d_in[1];
    const float* ye = (const float*)d_in[2];
    float* out = (float*)d_out;
    float* ws  = (float*)d_ws;

    float* dist = ws;
    float* sv   = ws + OFF_SV;
    int*   sd   = (int*)(ws + OFF_SD);
    float* cv   = ws + OFF_CV;
    int*   ci   = (int*)(ws + OFF_CI);
    float* xT   = ws + OFF_XT;
    float* yeP  = ws + OFF_YEP;
    float* xeP  = ws + OFF_XEP;

    {
        int total = XTW*XTW + YEH*YEW + XEH*XEW;
        hipLaunchKernelGGL(k_prep, dim3((total + 255)/256), dim3(256), 0, stream,
                           x, xe, ye, xT, xeP, yeP);
    }
    hipLaunchKernelGGL(k_dist,  dim3(8*29*7), dim3(128), 0, stream, xeP, yeP, dist);
    hipLaunchKernelGGL(k_topkA, dim3(151*4), dim3(256), 0, stream, dist, cv, ci);
    hipLaunchKernelGGL(k_topkB, dim3((QN + 255)/256), dim3(256), 0, stream, cv, ci, sv, sd);
    hipLaunchKernelGGL(k_agg,   dim3(24*24), dim3(512), 0, stream, xT, sv, sd, out);
}

// Round 7
// 78.962 us; speedup vs baseline: 3.4783x; 1.0020x over previous
//
#include <hip/hip_runtime.h>

// ---- problem constants ----
#define PS   10
#define KNN  7
#define WSZ  29
#define RR   14
#define IH   96
#define IW   96
#define CH   16
#define CE   8
#define HH   98            // query grid (after pad1)
#define QN   (HH*HH)       // 9604 queries
#define ND   (WSZ*WSZ)     // 841 displacements
#define XTW  124           // padded x-interleaved: coords [-14,109]
#define XTP  14
#define YEW  107
#define YEH  112
#define XEW  144
#define XEH  140
#define QP   9800          // dist plane pitch (98 rows x 100)

// ---- ws layout (float units) ----
#define OFF_SV   8241856ull                 // align64(841*9800)
#define OFF_SD   (OFF_SV + 76832ull)
#define OFF_CV   (OFF_SD + 76832ull)        // stage-A candidates: QN*4*8
#define OFF_CI   (OFF_CV + 307328ull)
#define OFF_XT   (OFF_CI + 307328ull)
#define OFF_YEP  (OFF_XT + 246016ull)
#define OFF_XEP  (OFF_YEP + 95872ull)
// end = OFF_XEP + 161280 = 9,513,344 floats = 38.1 MB

__device__ __forceinline__ int imin(int a, int b){ return a<b?a:b; }
__device__ __forceinline__ int imax(int a, int b){ return a>b?a:b; }

// ---- K0: pack x -> xT[124][124][16]; ye -> yeP[112][107][8]; xe -> xeP[140][144][8]
__global__ __launch_bounds__(256) void k_prep(const float* __restrict__ x,
                                              const float* __restrict__ xe,
                                              const float* __restrict__ ye,
                                              float* __restrict__ xT,
                                              float* __restrict__ xeP,
                                              float* __restrict__ yeP) {
    int t = blockIdx.x*256 + threadIdx.x;
    if (t < XTW*XTW) {
        int u = t / XTW, v = t % XTW;
        int ui = u - XTP, vi = v - XTP;
        bool inb = ((unsigned)ui < (unsigned)IH) && ((unsigned)vi < (unsigned)IW);
        int off = inb ? (ui*IW + vi) : 0;
        float4* dst = (float4*)(xT + (size_t)t*CH);
        #pragma unroll
        for (int c4 = 0; c4 < 4; ++c4) {
            float4 val;
            val.x = inb ? x[(c4*4+0)*IH*IW + off] : 0.f;
            val.y = inb ? x[(c4*4+1)*IH*IW + off] : 0.f;
            val.z = inb ? x[(c4*4+2)*IH*IW + off] : 0.f;
            val.w = inb ? x[(c4*4+3)*IH*IW + off] : 0.f;
            dst[c4] = val;
        }
        return;
    }
    t -= XTW*XTW;
    if (t < YEH*YEW) {
        int i = t / YEW, j = t % YEW;
        bool inb = ((unsigned)(i-6) < (unsigned)IH) && ((unsigned)(j-6) < (unsigned)IW);
        int off = inb ? ((i-6)*IW + (j-6)) : 0;
        float4* dst = (float4*)(yeP + (size_t)t*CE);
        #pragma unroll
        for (int c4 = 0; c4 < 2; ++c4) {
            float4 val;
            val.x = inb ? ye[(c4*4+0)*IH*IW + off] : 0.f;
            val.y = inb ? ye[(c4*4+1)*IH*IW + off] : 0.f;
            val.z = inb ? ye[(c4*4+2)*IH*IW + off] : 0.f;
            val.w = inb ? ye[(c4*4+3)*IH*IW + off] : 0.f;
            dst[c4] = val;
        }
        return;
    }
    t -= YEH*YEW;
    if (t < XEH*XEW) {
        int i = t / XEW, j = t % XEW;
        bool inb = ((unsigned)(i-20) < (unsigned)IH) && ((unsigned)(j-20) < (unsigned)IW);
        int off = inb ? ((i-20)*IW + (j-20)) : 0;
        float4* dst = (float4*)(xeP + (size_t)t*CE);
        #pragma unroll
        for (int c4 = 0; c4 < 2; ++c4) {
            float4 val;
            val.x = inb ? xe[(c4*4+0)*IH*IW + off] : 0.f;
            val.y = inb ? xe[(c4*4+1)*IH*IW + off] : 0.f;
            val.z = inb ? xe[(c4*4+2)*IH*IW + off] : 0.f;
            val.w = inb ? xe[(c4*4+3)*IH*IW + off] : 0.f;
            dst[c4] = val;
        }
    }
}

// ---- K1: distances, BARRIER-FREE wave-private design ----
// block = (dy-group of 4, dx, 14-row strip). grid = 8*29*7 = 1624, 128 thr.
// wave 0 owns cols 0..63 (outputs x0 0..51); wave 1 owns cols 43..106
// (outputs 52..97). Horizontal pass reads only the wave's own LDS region:
// in-wave DS program order suffices -> no __syncthreads anywhere.
__global__ __launch_bounds__(128, 4) void k_dist(const float* __restrict__ xeP,
                                                 const float* __restrict__ yeP,
                                                 float* __restrict__ dist) {
    __shared__ float cs[2][4][72];       // 2.3 KB, wave-private halves

    int b     = blockIdx.x;
    int dx_i  = b % 29;
    int rem   = b / 29;
    int strip = rem % 7;
    int dyg   = rem / 7;                 // 0..7
    int y0s   = strip * 14;
    int tid   = threadIdx.x;
    int wid   = tid >> 6;
    int lane  = tid & 63;
    int col   = wid ? (43 + lane) : lane;     // owned column (0..106)
    int widx  = lane + (wid ? 3 : 0);         // LDS region index = col-40 (w1) / col (w0)

    // ---- phase-C (horizontal) assignment, wave-local ----
    int nun   = wid ? 12 : 13;                // units per dyi
    int dyi_c = imin(lane / nun, 3);
    int u     = lane - dyi_c * nun;
    bool cact = lane < nun * 4;
    int x0u   = wid ? (52 + 4*u) : (4*u);
    bool full4 = (wid == 0) || (u < 11);      // wave1 u=11 -> float2 at x0=96
    const float* rdp = &cs[wid][dyi_c][ wid ? (12 + 4*u) : (4*u) ];
    int plane = dyg*4 + dyi_c;
    bool plane_ok = cact && (plane <= 28);
    int dy_c  = plane - 14;
    int dx    = dx_i - 14;
    bool selfd = (dy_c == 0) && (dx == 0);
    bool okx0 = (unsigned)(x0u+0+dx) < 98u;
    bool okx1 = (unsigned)(x0u+1+dx) < 98u;
    bool okx2 = (unsigned)(x0u+2+dx) < 98u;
    bool okx3 = (unsigned)(x0u+3+dx) < 98u;
    float* dout = dist + (size_t)(imin(plane,28)*29 + dx_i)*QP + x0u;   // FIX: *29 + dx_i

    // ---- streaming pointers ----
    const size_t xstep = (size_t)XEW*CE, ystep = (size_t)YEW*CE;
    const float* xload = xeP + ((size_t)(y0s + dyg*4)*XEW + (col + dx_i))*CE;
    const float* yload = yeP + ((size_t)y0s*YEW + col)*CE;

    float4 xr[5][2];
    #pragma unroll
    for (int r = 0; r < 4; ++r) {
        xr[r][0] = ((const float4*)xload)[0];
        xr[r][1] = ((const float4*)xload)[1];
        xload += xstep;
    }
    float wsum[4] = {0.f,0.f,0.f,0.f};
    float hist[4][10];

#define DSTEP(S) { \
    float4 xna = ((const float4*)xload)[0]; \
    float4 xnb = ((const float4*)xload)[1]; \
    xload += xstep; \
    float4 ya  = ((const float4*)yload)[0]; \
    float4 yb  = ((const float4*)yload)[1]; \
    yload += ystep; \
    xr[(S+4)%5][0] = xna; xr[(S+4)%5][1] = xnb; \
    _Pragma("unroll") \
    for (int dyi = 0; dyi < 4; ++dyi) { \
        float4 xa = xr[(S+dyi)%5][0]; \
        float4 xb = xr[(S+dyi)%5][1]; \
        float d0=ya.x-xa.x, d1=ya.y-xa.y, d2=ya.z-xa.z, d3=ya.w-xa.w; \
        float d4=yb.x-xb.x, d5=yb.y-xb.y, d6=yb.z-xb.z, d7=yb.w-xb.w; \
        float a = d0*d0; \
        a=fmaf(d1,d1,a); a=fmaf(d2,d2,a); a=fmaf(d3,d3,a); \
        a=fmaf(d4,d4,a); a=fmaf(d5,d5,a); a=fmaf(d6,d6,a); \
        a=fmaf(d7,d7,a); \
        float w = wsum[dyi] + a; \
        if ((S) >= 10) w -= hist[dyi][(S)%10]; \
        wsum[dyi] = w; \
        hist[dyi][(S)%10] = a; \
        cs[wid][dyi][widx] = w; \
    } \
    if ((S) >= 9 && plane_ok) { \
        float v0=rdp[0], v1=rdp[1], v2=rdp[2], v3=rdp[3]; \
        float v4=rdp[4], v5=rdp[5], v6=rdp[6], v7=rdp[7]; \
        float v8=rdp[8], v9=rdp[9], v10=rdp[10], v11=rdp[11], v12=rdp[12]; \
        float s0 = ((v0+v1)+(v2+v3)) + ((v4+v5)+(v6+v7)) + (v8+v9); \
        float s1 = s0 - v0 + v10; \
        float s2 = s1 - v1 + v11; \
        float s3 = s2 - v2 + v12; \
        int y0 = y0s + (S) - 9; \
        bool okr = ((unsigned)(y0 + dy_c) < 98u) && !selfd; \
        float4 o; \
        o.x = (okr && okx0) ? s0 : 1e10f; \
        o.y = (okr && okx1) ? s1 : 1e10f; \
        o.z = (okr && okx2) ? s2 : 1e10f; \
        o.w = (okr && okx3) ? s3 : 1e10f; \
        if (full4) *(float4*)(dout + y0*100) = o; \
        else       *(float2*)(dout + y0*100) = make_float2(o.x, o.y); \
    } \
}

    DSTEP(0)  DSTEP(1)  DSTEP(2)  DSTEP(3)  DSTEP(4)
    DSTEP(5)  DSTEP(6)  DSTEP(7)  DSTEP(8)  DSTEP(9)
    DSTEP(10) DSTEP(11) DSTEP(12) DSTEP(13) DSTEP(14)
    DSTEP(15) DSTEP(16) DSTEP(17) DSTEP(18) DSTEP(19)
    DSTEP(20) DSTEP(21) DSTEP(22)
#undef DSTEP
}

// ---- K2a: stage-A top-7 per (query, displacement-quarter). grid 151*4 ----
__global__ __launch_bounds__(256) void k_topkA(const float* __restrict__ dist,
                                               float* __restrict__ cv, int* __restrict__ ci) {
    __shared__ float lv[3*64*8];
    __shared__ int   lix[3*64*8];
    int wv = threadIdx.x >> 6, ln = threadIdx.x & 63;
    int qb = blockIdx.x % 151;
    int rg = blockIdx.x / 151;           // 0..3
    int q  = qb*64 + ln;
    int qq = q < QN ? q : QN-1;
    int y0 = qq / 98, x0 = qq - y0*98;
    int off = y0*100 + x0;

    int rbase = rg*210 + (rg > 0 ? 1 : 0);   // 0,211,421,631
    int ndr   = (rg == 0) ? 211 : 210;
    int s0 = rbase + wv*53;
    int s1 = imin(rbase + ndr, s0 + 53);

    float ld[KNN]; int li[KNN];
    #pragma unroll
    for (int k = 0; k < KNN; ++k) { ld[k] = 1e30f; li[k] = -1; }

    auto INS = [&](float v, int dsp) {
        float cvv = v; int cii = dsp;
        #pragma unroll
        for (int k = 0; k < KNN; ++k) {
            bool sw = cvv < ld[k];
            float tf = ld[k]; int ti = li[k];
            ld[k] = sw ? cvv : tf;  li[k] = sw ? cii : ti;
            cvv   = sw ? tf : cvv;  cii   = sw ? ti : cii;
        }
    };

    #pragma unroll 2
    for (int dd = s0; dd < s1; ++dd)
        INS(dist[(size_t)dd*QP + off], dd);

    if (wv) {
        int bse = ((wv-1)*64 + ln)*8;
        #pragma unroll
        for (int r = 0; r < KNN; ++r) { lv[bse+r] = ld[r]; lix[bse+r] = li[r]; }
    }
    __syncthreads();
    if (wv == 0 && q < QN) {
        #pragma unroll
        for (int w = 0; w < 3; ++w) {
            int bse = (w*64 + ln)*8;
            #pragma unroll
            for (int r = 0; r < KNN; ++r) INS(lv[bse+r], lix[bse+r]);
        }
        #pragma unroll
        for (int r = 0; r < KNN; ++r) {
            cv[(q*4 + rg)*8 + r] = ld[r];
            ci[(q*4 + rg)*8 + r] = li[r];
        }
    }
}

// ---- K2b: merge 28 candidates per query, softmax, delta conversion ----
__global__ __launch_bounds__(256) void k_topkB(const float* __restrict__ cv,
                                               const int* __restrict__ ci,
                                               float* __restrict__ sv, int* __restrict__ sd) {
    int q = blockIdx.x*256 + threadIdx.x;
    if (q >= QN) return;

    float ld[KNN]; int li[KNN];
    #pragma unroll
    for (int k = 0; k < KNN; ++k) { ld[k] = 1e30f; li[k] = -1; }

    auto INS = [&](float v, int dsp) {
        float cvv = v; int cii = dsp;
        #pragma unroll
        for (int k = 0; k < KNN; ++k) {
            bool sw = cvv < ld[k];
            float tf = ld[k]; int ti = li[k];
            ld[k] = sw ? cvv : tf;  li[k] = sw ? cii : ti;
            cvv   = sw ? tf : cvv;  cii   = sw ? ti : cii;
        }
    };

    #pragma unroll
    for (int rg = 0; rg < 4; ++rg) {
        #pragma unroll
        for (int r = 0; r < KNN; ++r)
            INS(cv[(q*4 + rg)*8 + r], ci[(q*4 + rg)*8 + r]);
    }

    float e[KNN]; float ssum = 0.f;
    #pragma unroll
    for (int r = 0; r < KNN; ++r) { e[r] = __expf(ld[0] - ld[r]); ssum += e[r]; }
    float inv = 1.f / ssum;
    #pragma unroll
    for (int r = 0; r < KNN; ++r) {
        sv[q*8 + r] = e[r] * inv;
        int dsp = li[r];
        int dyk = dsp / WSZ - RR, dxk = dsp % WSZ - RR;
        sd[q*8 + r] = (dyk*XTW + dxk) * CH;    // float-unit delta into xT
    }
}

// ---- K3: aggregation. block = 4x4 pixel tile x 4 quads x 8 (oy,ox)-groups ----
__global__ __launch_bounds__(512) void k_agg(const float* __restrict__ xT,
                                             const float* __restrict__ wgt,
                                             const int* __restrict__ dlt,
                                             float* __restrict__ out) {
    __shared__ float2 lw[13*13*7];    // 9.5 KB staged (w, delta)
    __shared__ float4 red[7*64];      // 7 KB
    int tid = threadIdx.x;
    int tb = blockIdx.x;
    int ai0 = (tb / 24) * 4, bi0 = (tb % 24) * 4;

    for (int u = tid; u < 13*13*7; u += 512) {
        int lq = u / 7, k = u - lq*7;
        int lqi = lq / 13, lqj = lq - lqi*13;
        int qi = ai0 - 3 + lqi, qj = bi0 - 3 + lqj;
        bool ok = ((unsigned)qi < 98u) && ((unsigned)qj < 98u);
        int q = ok ? (qi*98 + qj) : 0;
        float w = ok ? wgt[q*8 + k] : 0.f;
        int  dl = ok ? dlt[q*8 + k] : 0;
        lw[u] = make_float2(w, __int_as_float(dl));
    }
    __syncthreads();

    int og   = tid >> 6;          // 0..7
    int rem  = tid & 63;
    int quad = rem & 3;
    int pl   = rem >> 2;          // 0..15
    int py   = pl >> 2, px = pl & 3;
    int ai = ai0 + py, bi = bi0 + px;
    int base = ((ai + XTP)*XTW + (bi + XTP))*CH + quad*4;

    float ax=0.f, ay=0.f, az=0.f, aw=0.f;
    #pragma unroll
    for (int c = 0; c < 13; ++c) {
        int u = og*13 + c;
        if (u >= 100) break;
        int oy = u / 10, ox = u - oy*10;
        int lq = (py + 9 - oy)*13 + (px + 9 - ox);
        const float2* f2p = lw + lq*7;
        #pragma unroll
        for (int k = 0; k < KNN; ++k) {
            float2 wd = f2p[k];
            int dl = __float_as_int(wd.y);
            const float4 xv = *(const float4*)(xT + base + dl);
            ax = fmaf(wd.x, xv.x, ax); ay = fmaf(wd.x, xv.y, ay);
            az = fmaf(wd.x, xv.z, az); aw = fmaf(wd.x, xv.w, aw);
        }
    }

    if (og) {
        float4 pr; pr.x=ax; pr.y=ay; pr.z=az; pr.w=aw;
        red[(og-1)*64 + rem] = pr;
    }
    __syncthreads();
    if (og == 0) {
        #pragma unroll
        for (int w = 0; w < 7; ++w) {
            float4 pr = red[w*64 + rem];
            ax += pr.x; ay += pr.y; az += pr.z; aw += pr.w;
        }
        int i = ai + 6, j = bi + 6;
        float cr = (float)(imin(i, 97) - imax(i - 9, 0) + 1);
        float cc = (float)(imin(j, 97) - imax(j - 9, 0) + 1);
        float inv = 1.f / (cr * cc);
        float4 xs = *(const float4*)(xT + base);
        int p = ai*IW + bi;
        int ch0 = quad*4;
        out[(ch0+0)*IH*IW + p] = xs.x;
        out[(ch0+1)*IH*IW + p] = xs.y;
        out[(ch0+2)*IH*IW + p] = xs.z;
        out[(ch0+3)*IH*IW + p] = xs.w;
        out[(16+ch0+0)*IH*IW + p] = ax*inv - xs.x;
        out[(16+ch0+1)*IH*IW + p] = ay*inv - xs.y;
        out[(16+ch0+2)*IH*IW + p] = az*inv - xs.z;
        out[(16+ch0+3)*IH*IW + p] = aw*inv - xs.w;
    }
}

extern "C" void kernel_launch(void* const* d_in, const int* in_sizes, int n_in,
                              void* d_out, int out_size, void* d_ws, size_t ws_size,
                              hipStream_t stream) {
    const float* x  = (const float*)d_in[0];
    const float* xe = (const float*)d_in[1];
    const float* ye = (const float*)d_in[2];
    float* out = (float*)d_out;
    float* ws  = (float*)d_ws;

    float* dist = ws;
    float* sv   = ws + OFF_SV;
    int*   sd   = (int*)(ws + OFF_SD);
    float* cv   = ws + OFF_CV;
    int*   ci   = (int*)(ws + OFF_CI);
    float* xT   = ws + OFF_XT;
    float* yeP  = ws + OFF_YEP;
    float* xeP  = ws + OFF_XEP;

    {
        int total = XTW*XTW + YEH*YEW + XEH*XEW;
        hipLaunchKernelGGL(k_prep, dim3((total + 255)/256), dim3(256), 0, stream,
                           x, xe, ye, xT, xeP, yeP);
    }
    hipLaunchKernelGGL(k_dist,  dim3(8*29*7), dim3(128), 0, stream, xeP, yeP, dist);
    hipLaunchKernelGGL(k_topkA, dim3(151*4), dim3(256), 0, stream, dist, cv, ci);
    hipLaunchKernelGGL(k_topkB, dim3((QN + 255)/256), dim3(256), 0, stream, cv, ci, sv, sd);
    hipLaunchKernelGGL(k_agg,   dim3(24*24), dim3(512), 0, stream, xT, sv, sd, out);
}

// Round 8
// 72.620 us; speedup vs baseline: 3.7820x; 1.0873x over previous
//
#include <hip/hip_runtime.h>

// ---- problem constants ----
#define PS   10
#define KNN  7
#define WSZ  29
#define RR   14
#define IH   96
#define IW   96
#define CH   16
#define CE   8
#define HH   98            // query grid (after pad1)
#define QN   (HH*HH)       // 9604 queries
#define ND   (WSZ*WSZ)     // 841 displacements
#define XTW  124           // padded x (bf16): coords [-14,109]
#define XTP  14
#define YEW  107
#define YEH  112
#define XEW  144
#define XEH  140
#define QP   9800          // dist plane pitch (98 rows x 100)

// ---- ws layout (float units) ----
#define OFF_CV   8241856ull                 // align64(841*9800); candidates QN*4*8
#define OFF_CI   (OFF_CV + 307328ull)
#define OFF_XT   (OFF_CI + 307328ull)       // bf16 x: 124*124*16 ushort = 123008 fl
#define OFF_YEP  (OFF_XT + 123072ull)
#define OFF_XEP  (OFF_YEP + 95872ull)
// end = OFF_XEP + 161280 = 9,236,736 floats = 37 MB

__device__ __forceinline__ int imin(int a, int b){ return a<b?a:b; }
__device__ __forceinline__ int imax(int a, int b){ return a>b?a:b; }
__device__ __forceinline__ unsigned short f2bf(float f){
    unsigned u = __float_as_uint(f);
    return (unsigned short)((u + 0x7fffu + ((u >> 16) & 1u)) >> 16);
}

// ---- K0: pack x -> bf16 xTb[124][124][16]; ye -> yeP[112][107][8]; xe -> xeP[140][144][8]
__global__ __launch_bounds__(256) void k_prep(const float* __restrict__ x,
                                              const float* __restrict__ xe,
                                              const float* __restrict__ ye,
                                              unsigned short* __restrict__ xTb,
                                              float* __restrict__ xeP,
                                              float* __restrict__ yeP) {
    int t = blockIdx.x*256 + threadIdx.x;
    if (t < XTW*XTW) {
        int u = t / XTW, v = t % XTW;
        int ui = u - XTP, vi = v - XTP;
        bool inb = ((unsigned)ui < (unsigned)IH) && ((unsigned)vi < (unsigned)IW);
        int off = inb ? (ui*IW + vi) : 0;
        unsigned d[8];
        #pragma unroll
        for (int j = 0; j < 8; ++j) {
            float a = inb ? x[(2*j+0)*IH*IW + off] : 0.f;
            float b = inb ? x[(2*j+1)*IH*IW + off] : 0.f;
            d[j] = (unsigned)f2bf(a) | ((unsigned)f2bf(b) << 16);
        }
        uint4* dst = (uint4*)(xTb + (size_t)t*CH);
        dst[0] = make_uint4(d[0], d[1], d[2], d[3]);
        dst[1] = make_uint4(d[4], d[5], d[6], d[7]);
        return;
    }
    t -= XTW*XTW;
    if (t < YEH*YEW) {
        int i = t / YEW, j = t % YEW;
        bool inb = ((unsigned)(i-6) < (unsigned)IH) && ((unsigned)(j-6) < (unsigned)IW);
        int off = inb ? ((i-6)*IW + (j-6)) : 0;
        float4* dst = (float4*)(yeP + (size_t)t*CE);
        #pragma unroll
        for (int c4 = 0; c4 < 2; ++c4) {
            float4 val;
            val.x = inb ? ye[(c4*4+0)*IH*IW + off] : 0.f;
            val.y = inb ? ye[(c4*4+1)*IH*IW + off] : 0.f;
            val.z = inb ? ye[(c4*4+2)*IH*IW + off] : 0.f;
            val.w = inb ? ye[(c4*4+3)*IH*IW + off] : 0.f;
            dst[c4] = val;
        }
        return;
    }
    t -= YEH*YEW;
    if (t < XEH*XEW) {
        int i = t / XEW, j = t % XEW;
        bool inb = ((unsigned)(i-20) < (unsigned)IH) && ((unsigned)(j-20) < (unsigned)IW);
        int off = inb ? ((i-20)*IW + (j-20)) : 0;
        float4* dst = (float4*)(xeP + (size_t)t*CE);
        #pragma unroll
        for (int c4 = 0; c4 < 2; ++c4) {
            float4 val;
            val.x = inb ? xe[(c4*4+0)*IH*IW + off] : 0.f;
            val.y = inb ? xe[(c4*4+1)*IH*IW + off] : 0.f;
            val.z = inb ? xe[(c4*4+2)*IH*IW + off] : 0.f;
            val.w = inb ? xe[(c4*4+3)*IH*IW + off] : 0.f;
            dst[c4] = val;
        }
    }
}

// ---- K1: distances, BARRIER-FREE wave-private design (unchanged from R7) ----
__global__ __launch_bounds__(128, 4) void k_dist(const float* __restrict__ xeP,
                                                 const float* __restrict__ yeP,
                                                 float* __restrict__ dist) {
    __shared__ float cs[2][4][72];       // 2.3 KB, wave-private halves

    int b     = blockIdx.x;
    int dx_i  = b % 29;
    int rem   = b / 29;
    int strip = rem % 7;
    int dyg   = rem / 7;                 // 0..7
    int y0s   = strip * 14;
    int tid   = threadIdx.x;
    int wid   = tid >> 6;
    int lane  = tid & 63;
    int col   = wid ? (43 + lane) : lane;
    int widx  = lane + (wid ? 3 : 0);

    int nun   = wid ? 12 : 13;
    int dyi_c = imin(lane / nun, 3);
    int u     = lane - dyi_c * nun;
    bool cact = lane < nun * 4;
    int x0u   = wid ? (52 + 4*u) : (4*u);
    bool full4 = (wid == 0) || (u < 11);
    const float* rdp = &cs[wid][dyi_c][ wid ? (12 + 4*u) : (4*u) ];
    int plane = dyg*4 + dyi_c;
    bool plane_ok = cact && (plane <= 28);
    int dy_c  = plane - 14;
    int dx    = dx_i - 14;
    bool selfd = (dy_c == 0) && (dx == 0);
    bool okx0 = (unsigned)(x0u+0+dx) < 98u;
    bool okx1 = (unsigned)(x0u+1+dx) < 98u;
    bool okx2 = (unsigned)(x0u+2+dx) < 98u;
    bool okx3 = (unsigned)(x0u+3+dx) < 98u;
    float* dout = dist + (size_t)(imin(plane,28)*29 + dx_i)*QP + x0u;

    const size_t xstep = (size_t)XEW*CE, ystep = (size_t)YEW*CE;
    const float* xload = xeP + ((size_t)(y0s + dyg*4)*XEW + (col + dx_i))*CE;
    const float* yload = yeP + ((size_t)y0s*YEW + col)*CE;

    float4 xr[5][2];
    #pragma unroll
    for (int r = 0; r < 4; ++r) {
        xr[r][0] = ((const float4*)xload)[0];
        xr[r][1] = ((const float4*)xload)[1];
        xload += xstep;
    }
    float wsum[4] = {0.f,0.f,0.f,0.f};
    float hist[4][10];

#define DSTEP(S) { \
    float4 xna = ((const float4*)xload)[0]; \
    float4 xnb = ((const float4*)xload)[1]; \
    xload += xstep; \
    float4 ya  = ((const float4*)yload)[0]; \
    float4 yb  = ((const float4*)yload)[1]; \
    yload += ystep; \
    xr[(S+4)%5][0] = xna; xr[(S+4)%5][1] = xnb; \
    _Pragma("unroll") \
    for (int dyi = 0; dyi < 4; ++dyi) { \
        float4 xa = xr[(S+dyi)%5][0]; \
        float4 xb = xr[(S+dyi)%5][1]; \
        float d0=ya.x-xa.x, d1=ya.y-xa.y, d2=ya.z-xa.z, d3=ya.w-xa.w; \
        float d4=yb.x-xb.x, d5=yb.y-xb.y, d6=yb.z-xb.z, d7=yb.w-xb.w; \
        float a = d0*d0; \
        a=fmaf(d1,d1,a); a=fmaf(d2,d2,a); a=fmaf(d3,d3,a); \
        a=fmaf(d4,d4,a); a=fmaf(d5,d5,a); a=fmaf(d6,d6,a); \
        a=fmaf(d7,d7,a); \
        float w = wsum[dyi] + a; \
        if ((S) >= 10) w -= hist[dyi][(S)%10]; \
        wsum[dyi] = w; \
        hist[dyi][(S)%10] = a; \
        cs[wid][dyi][widx] = w; \
    } \
    if ((S) >= 9 && plane_ok) { \
        float v0=rdp[0], v1=rdp[1], v2=rdp[2], v3=rdp[3]; \
        float v4=rdp[4], v5=rdp[5], v6=rdp[6], v7=rdp[7]; \
        float v8=rdp[8], v9=rdp[9], v10=rdp[10], v11=rdp[11], v12=rdp[12]; \
        float s0 = ((v0+v1)+(v2+v3)) + ((v4+v5)+(v6+v7)) + (v8+v9); \
        float s1 = s0 - v0 + v10; \
        float s2 = s1 - v1 + v11; \
        float s3 = s2 - v2 + v12; \
        int y0 = y0s + (S) - 9; \
        bool okr = ((unsigned)(y0 + dy_c) < 98u) && !selfd; \
        float4 o; \
        o.x = (okr && okx0) ? s0 : 1e10f; \
        o.y = (okr && okx1) ? s1 : 1e10f; \
        o.z = (okr && okx2) ? s2 : 1e10f; \
        o.w = (okr && okx3) ? s3 : 1e10f; \
        if (full4) *(float4*)(dout + y0*100) = o; \
        else       *(float2*)(dout + y0*100) = make_float2(o.x, o.y); \
    } \
}

    DSTEP(0)  DSTEP(1)  DSTEP(2)  DSTEP(3)  DSTEP(4)
    DSTEP(5)  DSTEP(6)  DSTEP(7)  DSTEP(8)  DSTEP(9)
    DSTEP(10) DSTEP(11) DSTEP(12) DSTEP(13) DSTEP(14)
    DSTEP(15) DSTEP(16) DSTEP(17) DSTEP(18) DSTEP(19)
    DSTEP(20) DSTEP(21) DSTEP(22)
#undef DSTEP
}

// ---- K2: stage-A top-7 per (query, displacement-quarter). grid 151*4 ----
__global__ __launch_bounds__(256) void k_topkA(const float* __restrict__ dist,
                                               float* __restrict__ cv, int* __restrict__ ci) {
    __shared__ float lv[3*64*8];
    __shared__ int   lix[3*64*8];
    int wv = threadIdx.x >> 6, ln = threadIdx.x & 63;
    int qb = blockIdx.x % 151;
    int rg = blockIdx.x / 151;           // 0..3
    int q  = qb*64 + ln;
    int qq = q < QN ? q : QN-1;
    int y0 = qq / 98, x0 = qq - y0*98;
    int off = y0*100 + x0;

    int rbase = rg*210 + (rg > 0 ? 1 : 0);   // 0,211,421,631
    int ndr   = (rg == 0) ? 211 : 210;
    int s0 = rbase + wv*53;
    int s1 = imin(rbase + ndr, s0 + 53);

    float ld[KNN]; int li[KNN];
    #pragma unroll
    for (int k = 0; k < KNN; ++k) { ld[k] = 1e30f; li[k] = -1; }

    auto INS = [&](float v, int dsp) {
        float cvv = v; int cii = dsp;
        #pragma unroll
        for (int k = 0; k < KNN; ++k) {
            bool sw = cvv < ld[k];
            float tf = ld[k]; int ti = li[k];
            ld[k] = sw ? cvv : tf;  li[k] = sw ? cii : ti;
            cvv   = sw ? tf : cvv;  cii   = sw ? ti : cii;
        }
    };

    #pragma unroll 4
    for (int dd = s0; dd < s1; ++dd)
        INS(dist[(size_t)dd*QP + off], dd);

    if (wv) {
        int bse = ((wv-1)*64 + ln)*8;
        #pragma unroll
        for (int r = 0; r < KNN; ++r) { lv[bse+r] = ld[r]; lix[bse+r] = li[r]; }
    }
    __syncthreads();
    if (wv == 0 && q < QN) {
        #pragma unroll
        for (int w = 0; w < 3; ++w) {
            int bse = (w*64 + ln)*8;
            #pragma unroll
            for (int r = 0; r < KNN; ++r) INS(lv[bse+r], lix[bse+r]);
        }
        #pragma unroll
        for (int r = 0; r < KNN; ++r) {
            cv[(q*4 + rg)*8 + r] = ld[r];
            ci[(q*4 + rg)*8 + r] = li[r];
        }
    }
}

// ---- K3: merge+softmax staging, then bf16 gather aggregation ----
// block = 4x4 pixel tile, 256 thr = 8 (oy,ox)-groups x (16 px x 2 ch-halves)
__global__ __launch_bounds__(256) void k_agg(const float* __restrict__ x,
                                             const unsigned short* __restrict__ xTb,
                                             const float* __restrict__ cv,
                                             const int* __restrict__ ci,
                                             float* __restrict__ out) {
    __shared__ float2 lw[169*7];      // (w, delta_ushort_units) per halo query
    __shared__ float  red[7][8][32];  // og 1..7 partials, conflict-free layout
    int tid = threadIdx.x;
    int tb  = blockIdx.x;
    int ai0 = (tb / 24) * 4, bi0 = (tb % 24) * 4;

    // stage: per halo query merge 28 candidates -> top7 -> softmax -> (w, dl)
    if (tid < 169) {
        int lqi = tid / 13, lqj = tid - lqi*13;
        int qi = ai0 - 3 + lqi, qj = bi0 - 3 + lqj;
        bool ok = ((unsigned)qi < 98u) && ((unsigned)qj < 98u);
        float ld[KNN]; int li[KNN];
        #pragma unroll
        for (int k = 0; k < KNN; ++k) { ld[k] = 1e30f; li[k] = -1; }
        if (ok) {
            int q = qi*98 + qj;
            #pragma unroll
            for (int rg = 0; rg < 4; ++rg) {
                #pragma unroll
                for (int r = 0; r < KNN; ++r) {
                    float v  = cv[(q*4 + rg)*8 + r];
                    int dsp  = ci[(q*4 + rg)*8 + r];
                    float cvv = v; int cii = dsp;
                    #pragma unroll
                    for (int k = 0; k < KNN; ++k) {
                        bool sw = cvv < ld[k];
                        float tf = ld[k]; int ti = li[k];
                        ld[k] = sw ? cvv : tf;  li[k] = sw ? cii : ti;
                        cvv   = sw ? tf : cvv;  cii   = sw ? ti : cii;
                    }
                }
            }
            float e[KNN]; float ssum = 0.f;
            #pragma unroll
            for (int r = 0; r < KNN; ++r) { e[r] = __expf(ld[0] - ld[r]); ssum += e[r]; }
            float inv = 1.f / ssum;
            #pragma unroll
            for (int r = 0; r < KNN; ++r) {
                int dsp = li[r];
                int dyk = dsp / WSZ - RR, dxk = dsp % WSZ - RR;
                lw[tid*7 + r] = make_float2(e[r]*inv,
                                            __int_as_float((dyk*XTW + dxk)*CH));
            }
        } else {
            #pragma unroll
            for (int r = 0; r < KNN; ++r) lw[tid*7 + r] = make_float2(0.f, 0.f);
        }
    }
    __syncthreads();

    int og   = tid >> 5;          // 0..7 position groups
    int rem  = tid & 31;
    int half = rem & 1;           // channel half (0: ch0-7, 1: ch8-15)
    int pl   = rem >> 1;          // 0..15 pixel
    int py   = pl >> 2, px = pl & 3;
    int ai = ai0 + py, bi = bi0 + px;
    int baseu = ((ai + XTP)*XTW + (bi + XTP))*CH + half*8;

    float acc[8] = {0.f,0.f,0.f,0.f,0.f,0.f,0.f,0.f};
    #pragma unroll
    for (int c = 0; c < 13; ++c) {
        int u = og*13 + c;
        if (u >= 100) break;
        int oy = u / 10, ox = u - oy*10;
        int lq = (py + 9 - oy)*13 + (px + 9 - ox);
        const float2* f2p = lw + lq*7;
        #pragma unroll
        for (int k = 0; k < KNN; ++k) {
            float2 wd = f2p[k];
            float w = wd.x;
            int dl = __float_as_int(wd.y);
            const uint4 g = *(const uint4*)(xTb + baseu + dl);
            acc[0] = fmaf(w, __uint_as_float(g.x << 16),          acc[0]);
            acc[1] = fmaf(w, __uint_as_float(g.x & 0xffff0000u),  acc[1]);
            acc[2] = fmaf(w, __uint_as_float(g.y << 16),          acc[2]);
            acc[3] = fmaf(w, __uint_as_float(g.y & 0xffff0000u),  acc[3]);
            acc[4] = fmaf(w, __uint_as_float(g.z << 16),          acc[4]);
            acc[5] = fmaf(w, __uint_as_float(g.z & 0xffff0000u),  acc[5]);
            acc[6] = fmaf(w, __uint_as_float(g.w << 16),          acc[6]);
            acc[7] = fmaf(w, __uint_as_float(g.w & 0xffff0000u),  acc[7]);
        }
    }

    if (og) {
        #pragma unroll
        for (int c = 0; c < 8; ++c) red[og-1][c][rem] = acc[c];
    }
    __syncthreads();
    if (og == 0) {
        #pragma unroll
        for (int w = 0; w < 7; ++w)
            #pragma unroll
            for (int c = 0; c < 8; ++c) acc[c] += red[w][c][rem];

        int i = ai + 6, j = bi + 6;
        float cr = (float)(imin(i, 97) - imax(i - 9, 0) + 1);
        float cc = (float)(imin(j, 97) - imax(j - 9, 0) + 1);
        float inv = 1.f / (cr * cc);
        int p = ai*IW + bi;
        #pragma unroll
        for (int c = 0; c < 8; ++c) {
            int ch = half*8 + c;
            float xv = x[ch*IH*IW + p];           // exact f32 copy of y
            out[ch*IH*IW + p] = xv;
            out[(16 + ch)*IH*IW + p] = acc[c]*inv - xv;
        }
    }
}

extern "C" void kernel_launch(void* const* d_in, const int* in_sizes, int n_in,
                              void* d_out, int out_size, void* d_ws, size_t ws_size,
                              hipStream_t stream) {
    const float* x  = (const float*)d_in[0];
    const float* xe = (const float*)d_in[1];
    const float* ye = (const float*)d_in[2];
    float* out = (float*)d_out;
    float* ws  = (float*)d_ws;

    float* dist = ws;
    float* cv   = ws + OFF_CV;
    int*   ci   = (int*)(ws + OFF_CI);
    unsigned short* xTb = (unsigned short*)(ws + OFF_XT);
    float* yeP  = ws + OFF_YEP;
    float* xeP  = ws + OFF_XEP;

    {
        int total = XTW*XTW + YEH*YEW + XEH*XEW;
        hipLaunchKernelGGL(k_prep, dim3((total + 255)/256), dim3(256), 0, stream,
                           x, xe, ye, xTb, xeP, yeP);
    }
    hipLaunchKernelGGL(k_dist,  dim3(8*29*7), dim3(128), 0, stream, xeP, yeP, dist);
    hipLaunchKernelGGL(k_topkA, dim3(151*4), dim3(256), 0, stream, dist, cv, ci);
    hipLaunchKernelGGL(k_agg,   dim3(24*24), dim3(256), 0, stream, x, xTb, cv, ci, out);
}